// Round 1
// baseline (824.893 us; speedup 1.0000x reference)
//
#include <hip/hip_runtime.h>
#include <math.h>

#define TT 2048
#define DD 512
#define HEADS 8
#define DH 64
#define NI 4
#define DI 64
#define KSEL 128

__device__ __forceinline__ float sigmoidf_(float z) {
    return 1.0f / (1.0f + __expf(-z));
}

// ---------------------------------------------------------------------------
// Tiled fp32 GEMM: C[M,N] = A[M,K] @ B[K,N]; EPI==1: C = sigmoid(acc + bias[n])
// 64x64 tile, 256 threads, 4x4 micro-tile per thread. M%64==0, N%64==0, K%16==0.
// ---------------------------------------------------------------------------
template <int EPI>
__global__ __launch_bounds__(256) void gemm64(const float* __restrict__ A,
                                              const float* __restrict__ B,
                                              const float* __restrict__ bias,
                                              float* __restrict__ C,
                                              int M, int N, int K) {
    __shared__ float As[64][17];  // [m][k], pad 17 to spread banks
    __shared__ float Bs[16][64];  // [k][n]
    int tid = threadIdx.x;
    int bm = blockIdx.y * 64;
    int bn = blockIdx.x * 64;
    int tx = tid & 15, ty = tid >> 4;
    float acc[4][4] = {};
    for (int k0 = 0; k0 < K; k0 += 16) {
#pragma unroll
        for (int i = 0; i < 4; ++i) {
            int e = tid + i * 256;
            int m = e >> 4, kk = e & 15;
            As[m][kk] = A[(size_t)(bm + m) * K + k0 + kk];
        }
#pragma unroll
        for (int i = 0; i < 4; ++i) {
            int e = tid + i * 256;
            int kk = e >> 6, n = e & 63;
            Bs[kk][n] = B[(size_t)(k0 + kk) * N + bn + n];
        }
        __syncthreads();
#pragma unroll
        for (int kk = 0; kk < 16; ++kk) {
            float a[4], b[4];
#pragma unroll
            for (int i = 0; i < 4; ++i) a[i] = As[ty * 4 + i][kk];
#pragma unroll
            for (int j = 0; j < 4; ++j) b[j] = Bs[kk][tx * 4 + j];
#pragma unroll
            for (int i = 0; i < 4; ++i)
#pragma unroll
                for (int j = 0; j < 4; ++j) acc[i][j] += a[i] * b[j];
        }
        __syncthreads();
    }
#pragma unroll
    for (int i = 0; i < 4; ++i) {
        int m = bm + ty * 4 + i;
#pragma unroll
        for (int j = 0; j < 4; ++j) {
            int n = bn + tx * 4 + j;
            float v = acc[i][j];
            if (EPI == 1) v = sigmoidf_(v + bias[n]);
            C[(size_t)m * N + n] = v;
        }
    }
}

// ---------------------------------------------------------------------------
// wsig[t][c] = sigmoid(x[t,:] @ Wiw[:,c] + biw[c]),  c in [0,4)
// one block per row t; wave c computes column c
// ---------------------------------------------------------------------------
__global__ __launch_bounds__(256) void iw_kernel(const float* __restrict__ x,
                                                 const float* __restrict__ Wiw,
                                                 const float* __restrict__ biw,
                                                 float* __restrict__ wsig) {
    int t = blockIdx.x;
    int tid = threadIdx.x;
    int lane = tid & 63, c = tid >> 6;
    float acc = 0.f;
    for (int k = lane; k < DD; k += 64) acc += x[t * DD + k] * Wiw[k * NI + c];
#pragma unroll
    for (int off = 32; off; off >>= 1) acc += __shfl_down(acc, off);
    if (lane == 0) wsig[t * NI + c] = sigmoidf_(acc + biw[c]);
}

// v *= vg (elementwise)
__global__ void vmul_kernel(float* __restrict__ v, const float* __restrict__ vg) {
    int i = blockIdx.x * blockDim.x + threadIdx.x;
    v[i] *= vg[i];
}

// ---------------------------------------------------------------------------
// RoPE applied in-place to q and k. One thread per (t, h, j<32) pair.
// ---------------------------------------------------------------------------
__global__ void rope_kernel(float* __restrict__ q, float* __restrict__ k) {
    int i = blockIdx.x * blockDim.x + threadIdx.x;  // TT*HEADS*32 total
    int j = i & 31;
    int h = (i >> 5) & 7;
    int t = i >> 8;
    if (t >= TT) return;
    // inv_freq = 10000^(-j/32) = 2^(-j/32 * log2(10000))
    const float L2_10000 = 13.287712379549449f;
    float inv = exp2f(-(float)j * (1.0f / 32.0f) * L2_10000);
    float ang = (float)t * inv;
    float c = cosf(ang), s = sinf(ang);
    int base = t * DD + h * DH;
    float q1 = q[base + j], q2 = q[base + j + 32];
    q[base + j] = q1 * c - q2 * s;
    q[base + j + 32] = q2 * c + q1 * s;
    float k1 = k[base + j], k2 = k[base + j + 32];
    k[base + j] = k1 * c - k2 * s;
    k[base + j + 32] = k2 * c + k1 * s;
}

// ---------------------------------------------------------------------------
// Index scores + causal mask + top-K_SEL selection. One block per query row.
// score[k] = sum_h sigmoid(qi[q,h,:]�ki[k,:]/8 + idx_bias[h]) * wsig[q,h]
// ---------------------------------------------------------------------------
__global__ __launch_bounds__(256) void score_topk_kernel(
    const float* __restrict__ qi, const float* __restrict__ ki,
    const float* __restrict__ wsig, const float* __restrict__ idx_bias,
    int* __restrict__ indices, int* __restrict__ counts) {
    __shared__ float sc[TT];
    __shared__ float qil[NI * DI];
    __shared__ float reds[4];
    __shared__ int redi[4];
    int qrow = blockIdx.x;
    int tid = threadIdx.x;
    if (tid < NI * DI) qil[tid] = qi[qrow * (NI * DI) + tid];
    float wsl[NI], bl[NI];
#pragma unroll
    for (int h = 0; h < NI; ++h) {
        wsl[h] = wsig[qrow * NI + h];
        bl[h] = idx_bias[h];
    }
    __syncthreads();
    for (int k = tid; k < TT; k += 256) {
        float s;
        if (k <= qrow) {
            float a0 = 0, a1 = 0, a2 = 0, a3 = 0;
            const float* kr = ki + k * DI;
#pragma unroll 8
            for (int d = 0; d < DI; ++d) {
                float kv = kr[d];
                a0 += qil[d] * kv;
                a1 += qil[64 + d] * kv;
                a2 += qil[128 + d] * kv;
                a3 += qil[192 + d] * kv;
            }
            s = sigmoidf_(a0 * 0.125f + bl[0]) * wsl[0] +
                sigmoidf_(a1 * 0.125f + bl[1]) * wsl[1] +
                sigmoidf_(a2 * 0.125f + bl[2]) * wsl[2] +
                sigmoidf_(a3 * 0.125f + bl[3]) * wsl[3];
        } else {
            s = -1e30f;
        }
        sc[k] = s;
    }
    __syncthreads();
    int n = qrow + 1;
    if (n <= KSEL) {
        if (tid < n) indices[qrow * KSEL + tid] = tid;
        if (tid == 0) counts[qrow] = n;
        return;
    }
    if (tid == 0) counts[qrow] = KSEL;
    int lane = tid & 63, wid = tid >> 6;
    for (int it = 0; it < KSEL; ++it) {
        float bs = -1e30f;
        int bi = 0x7fffffff;
        for (int k = tid; k < TT; k += 256) {
            float v = sc[k];
            if (v > bs) { bs = v; bi = k; }  // ascending k => first max = lowest idx
        }
#pragma unroll
        for (int off = 32; off; off >>= 1) {
            float os = __shfl_down(bs, off);
            int oi = __shfl_down(bi, off);
            if (os > bs || (os == bs && oi < bi)) { bs = os; bi = oi; }
        }
        if (lane == 0) { reds[wid] = bs; redi[wid] = bi; }
        __syncthreads();
        if (tid == 0) {
            float b = reds[0];
            int bidx = redi[0];
#pragma unroll
            for (int wv = 1; wv < 4; ++wv) {
                if (reds[wv] > b || (reds[wv] == b && redi[wv] < bidx)) {
                    b = reds[wv];
                    bidx = redi[wv];
                }
            }
            indices[qrow * KSEL + it] = bidx;
            sc[bidx] = -2e30f;
        }
        __syncthreads();
    }
}

// ---------------------------------------------------------------------------
// Sparse attention over selected keys + og gate. One block per query row.
// ---------------------------------------------------------------------------
__global__ __launch_bounds__(256) void attn_kernel(
    const float* __restrict__ q, const float* __restrict__ k,
    const float* __restrict__ v, const float* __restrict__ og,
    const int* __restrict__ indices, const int* __restrict__ counts,
    float* __restrict__ out) {
    __shared__ float kt[KSEL * 65];
    __shared__ float vt[KSEL * 65];
    __shared__ float qv[DH];
    __shared__ float pp[KSEL];
    __shared__ int idx[KSEL];
    __shared__ float red[2];
    int qrow = blockIdx.x;
    int tid = threadIdx.x;
    int cnt = counts[qrow];
    if (tid < KSEL) idx[tid] = (tid < cnt) ? indices[qrow * KSEL + tid] : 0;
    __syncthreads();
    for (int h = 0; h < HEADS; ++h) {
        if (tid < DH) qv[tid] = q[qrow * DD + h * DH + tid];
        for (int e = tid; e < cnt * DH; e += 256) {
            int s = e >> 6, d = e & 63;
            int row = idx[s] * DD + h * DH + d;
            kt[s * 65 + d] = k[row];
            vt[s * 65 + d] = v[row];
        }
        __syncthreads();
        if (tid < KSEL) {
            float sval;
            if (tid < cnt) {
                float acc = 0.f;
#pragma unroll 8
                for (int d = 0; d < DH; ++d) acc += qv[d] * kt[tid * 65 + d];
                sval = acc * 0.125f;
            } else {
                sval = -1e30f;
            }
            pp[tid] = sval;
        }
        __syncthreads();
        if (tid < 64) {
            float m = fmaxf(pp[tid], pp[tid + 64]);
#pragma unroll
            for (int off = 32; off; off >>= 1) m = fmaxf(m, __shfl_down(m, off));
            if (tid == 0) red[0] = m;
        }
        __syncthreads();
        float mx = red[0];
        if (tid < KSEL) {
            float e = (tid < cnt) ? __expf(pp[tid] - mx) : 0.0f;
            pp[tid] = e;
        }
        __syncthreads();
        if (tid < 64) {
            float s = pp[tid] + pp[tid + 64];
#pragma unroll
            for (int off = 32; off; off >>= 1) s += __shfl_down(s, off);
            if (tid == 0) red[1] = s;
        }
        __syncthreads();
        float inv = 1.0f / red[1];
        if (tid < DH) {
            float acc = 0.f;
            for (int j = 0; j < cnt; ++j) acc += pp[j] * vt[j * 65 + tid];
            int o = qrow * DD + h * DH + tid;
            out[o] = acc * inv * og[o];
        }
        __syncthreads();
    }
}

// ---------------------------------------------------------------------------
extern "C" void kernel_launch(void* const* d_in, const int* in_sizes, int n_in,
                              void* d_out, int out_size, void* d_ws, size_t ws_size,
                              hipStream_t stream) {
    const float* x = (const float*)d_in[0];
    const float* Wq = (const float*)d_in[1];
    const float* Wk = (const float*)d_in[2];
    const float* Wv = (const float*)d_in[3];
    const float* Wo = (const float*)d_in[4];
    const float* Wiq = (const float*)d_in[5];
    const float* Wik = (const float*)d_in[6];
    const float* Wiw = (const float*)d_in[7];
    const float* biw = (const float*)d_in[8];
    const float* idx_bias = (const float*)d_in[9];
    const float* Wvg = (const float*)d_in[10];
    const float* bvg = (const float*)d_in[11];
    const float* Wog = (const float*)d_in[12];
    const float* bog = (const float*)d_in[13];
    float* out = (float*)d_out;
    float* ws = (float*)d_ws;

    float* qb = ws;                       // T*D
    float* kb = ws + (1 << 20);           // T*D
    float* vb = ws + (2 << 20);           // T*D
    float* vgb = ws + (3 << 20);          // T*D
    float* ogb = ws + (4 << 20);          // T*D
    float* qib = ws + (5 << 20);          // T*256
    float* kib = qib + TT * NI * DI;      // T*64
    float* wsb = kib + TT * DI;           // T*4
    float* ab = ws + (6 << 20);           // T*D (attention output, pre-Wo)
    int* idxb = (int*)(ws + (7 << 20));   // T*KSEL
    int* cntb = idxb + TT * KSEL;         // T

    dim3 blk(256);
    // projections
    gemm64<0><<<dim3(8, 32), blk, 0, stream>>>(x, Wq, nullptr, qb, TT, DD, DD);
    gemm64<0><<<dim3(8, 32), blk, 0, stream>>>(x, Wk, nullptr, kb, TT, DD, DD);
    gemm64<0><<<dim3(8, 32), blk, 0, stream>>>(x, Wv, nullptr, vb, TT, DD, DD);
    gemm64<1><<<dim3(8, 32), blk, 0, stream>>>(x, Wvg, bvg, vgb, TT, DD, DD);
    gemm64<1><<<dim3(8, 32), blk, 0, stream>>>(x, Wog, bog, ogb, TT, DD, DD);
    gemm64<0><<<dim3(4, 32), blk, 0, stream>>>(x, Wiq, nullptr, qib, TT, NI * DI, DD);
    gemm64<0><<<dim3(1, 32), blk, 0, stream>>>(x, Wik, nullptr, kib, TT, DI, DD);
    iw_kernel<<<TT, blk, 0, stream>>>(x, Wiw, biw, wsb);
    // v gating
    vmul_kernel<<<(TT * DD) / 256, blk, 0, stream>>>(vb, vgb);
    // RoPE on q,k
    rope_kernel<<<(TT * HEADS * 32) / 256, blk, 0, stream>>>(qb, kb);
    // index scores + top-k
    score_topk_kernel<<<TT, blk, 0, stream>>>(qib, kib, wsb, idx_bias, idxb, cntb);
    // sparse attention + og gate
    attn_kernel<<<TT, blk, 0, stream>>>(qb, kb, vb, ogb, idxb, cntb, ab);
    // output projection
    gemm64<0><<<dim3(8, 32), blk, 0, stream>>>(ab, Wo, nullptr, out, TT, DD, DD);
}

// Round 2
// 785.666 us; speedup vs baseline: 1.0499x; 1.0499x over previous
//
#include <hip/hip_runtime.h>
#include <math.h>

#define TT 2048
#define DD 512
#define HEADS 8
#define DH 64
#define NI 4
#define DI 64
#define KSEL 128

__device__ __forceinline__ float sigmoidf_(float z) {
    return 1.0f / (1.0f + __expf(-z));
}

// ---------------------------------------------------------------------------
// Tiled fp32 GEMM: C[M,N] = A[M,K] @ B[K,N]; EPI==1: C = sigmoid(acc + bias[n])
// 64x64 tile, 256 threads, 4x4 micro-tile per thread. M%64==0, N%64==0, K%16==0.
// ---------------------------------------------------------------------------
template <int EPI>
__global__ __launch_bounds__(256) void gemm64(const float* __restrict__ A,
                                              const float* __restrict__ B,
                                              const float* __restrict__ bias,
                                              float* __restrict__ C,
                                              int M, int N, int K) {
    __shared__ float As[64][17];
    __shared__ float Bs[16][64];
    int tid = threadIdx.x;
    int bm = blockIdx.y * 64;
    int bn = blockIdx.x * 64;
    int tx = tid & 15, ty = tid >> 4;
    float acc[4][4] = {};
    for (int k0 = 0; k0 < K; k0 += 16) {
#pragma unroll
        for (int i = 0; i < 4; ++i) {
            int e = tid + i * 256;
            int m = e >> 4, kk = e & 15;
            As[m][kk] = A[(size_t)(bm + m) * K + k0 + kk];
        }
#pragma unroll
        for (int i = 0; i < 4; ++i) {
            int e = tid + i * 256;
            int kk = e >> 6, n = e & 63;
            Bs[kk][n] = B[(size_t)(k0 + kk) * N + bn + n];
        }
        __syncthreads();
#pragma unroll
        for (int kk = 0; kk < 16; ++kk) {
            float a[4], b[4];
#pragma unroll
            for (int i = 0; i < 4; ++i) a[i] = As[ty * 4 + i][kk];
#pragma unroll
            for (int j = 0; j < 4; ++j) b[j] = Bs[kk][tx * 4 + j];
#pragma unroll
            for (int i = 0; i < 4; ++i)
#pragma unroll
                for (int j = 0; j < 4; ++j) acc[i][j] += a[i] * b[j];
        }
        __syncthreads();
    }
#pragma unroll
    for (int i = 0; i < 4; ++i) {
        int m = bm + ty * 4 + i;
#pragma unroll
        for (int j = 0; j < 4; ++j) {
            int n = bn + tx * 4 + j;
            float v = acc[i][j];
            if (EPI == 1) v = sigmoidf_(v + bias[n]);
            C[(size_t)m * N + n] = v;
        }
    }
}

__global__ __launch_bounds__(256) void iw_kernel(const float* __restrict__ x,
                                                 const float* __restrict__ Wiw,
                                                 const float* __restrict__ biw,
                                                 float* __restrict__ wsig) {
    int t = blockIdx.x;
    int tid = threadIdx.x;
    int lane = tid & 63, c = tid >> 6;
    float acc = 0.f;
    for (int k = lane; k < DD; k += 64) acc += x[t * DD + k] * Wiw[k * NI + c];
#pragma unroll
    for (int off = 32; off; off >>= 1) acc += __shfl_down(acc, off);
    if (lane == 0) wsig[t * NI + c] = sigmoidf_(acc + biw[c]);
}

__global__ void vmul_kernel(float* __restrict__ v, const float* __restrict__ vg) {
    int i = blockIdx.x * blockDim.x + threadIdx.x;
    v[i] *= vg[i];
}

__global__ void rope_kernel(float* __restrict__ q, float* __restrict__ k) {
    int i = blockIdx.x * blockDim.x + threadIdx.x;
    int j = i & 31;
    int h = (i >> 5) & 7;
    int t = i >> 8;
    if (t >= TT) return;
    const float L2_10000 = 13.287712379549449f;
    float inv = exp2f(-(float)j * (1.0f / 32.0f) * L2_10000);
    float ang = (float)t * inv;
    float c = cosf(ang), s = sinf(ang);
    int base = t * DD + h * DH;
    float q1 = q[base + j], q2 = q[base + j + 32];
    q[base + j] = q1 * c - q2 * s;
    q[base + j + 32] = q2 * c + q1 * s;
    float k1 = k[base + j], k2 = k[base + j + 32];
    k[base + j] = k1 * c - k2 * s;
    k[base + j + 32] = k2 * c + k1 * s;
}

// ---------------------------------------------------------------------------
// Index scores + causal mask + exact top-K via MSB-first radix select.
// One block of 256 threads per query row. Output index SET (order arbitrary;
// downstream softmax+sum are permutation invariant). Ties -> lowest index.
// ---------------------------------------------------------------------------
__global__ __launch_bounds__(256) void score_topk_kernel(
    const float* __restrict__ qi, const float* __restrict__ ki,
    const float* __restrict__ wsig, const float* __restrict__ idx_bias,
    int* __restrict__ indices, int* __restrict__ counts) {
    __shared__ unsigned ks_[TT];
    __shared__ float qil[NI * DI];
    __shared__ unsigned hist[256];
    __shared__ unsigned s_prefix, s_above;
    __shared__ int eqlist[256];
    __shared__ unsigned eqcount, outpos;
    int qrow = blockIdx.x;
    int tid = threadIdx.x;
    int n = qrow + 1;
    if (tid < NI * DI) qil[tid] = qi[qrow * (NI * DI) + tid];
    float wsl0 = wsig[qrow * NI + 0], wsl1 = wsig[qrow * NI + 1];
    float wsl2 = wsig[qrow * NI + 2], wsl3 = wsig[qrow * NI + 3];
    float bl0 = idx_bias[0], bl1 = idx_bias[1], bl2 = idx_bias[2], bl3 = idx_bias[3];
    __syncthreads();
    const float4* q4 = (const float4*)qil;
    // ---- scores: 8 keys/thread, processed 4 at a time with q-chunks in regs
#pragma unroll
    for (int p = 0; p < 2; ++p) {
        int kbase = tid + p * 1024;
        float a[4][4] = {};
        const float4* kr0 = (const float4*)(ki + (size_t)(kbase)*DI);
        const float4* kr1 = (const float4*)(ki + (size_t)(kbase + 256) * DI);
        const float4* kr2 = (const float4*)(ki + (size_t)(kbase + 512) * DI);
        const float4* kr3 = (const float4*)(ki + (size_t)(kbase + 768) * DI);
#pragma unroll
        for (int c = 0; c < 16; ++c) {
            float4 q0 = q4[c], q1 = q4[16 + c], q2 = q4[32 + c], q3 = q4[48 + c];
            float4 kv;
#define DOT4(J, KR)                                                     \
            kv = KR[c];                                                 \
            a[J][0] += q0.x * kv.x + q0.y * kv.y + q0.z * kv.z + q0.w * kv.w; \
            a[J][1] += q1.x * kv.x + q1.y * kv.y + q1.z * kv.z + q1.w * kv.w; \
            a[J][2] += q2.x * kv.x + q2.y * kv.y + q2.z * kv.z + q2.w * kv.w; \
            a[J][3] += q3.x * kv.x + q3.y * kv.y + q3.z * kv.z + q3.w * kv.w;
            DOT4(0, kr0)
            DOT4(1, kr1)
            DOT4(2, kr2)
            DOT4(3, kr3)
#undef DOT4
        }
#pragma unroll
        for (int j = 0; j < 4; ++j) {
            int k = kbase + j * 256;
            unsigned key = 0;
            if (k < n) {
                float s = sigmoidf_(a[j][0] * 0.125f + bl0) * wsl0 +
                          sigmoidf_(a[j][1] * 0.125f + bl1) * wsl1 +
                          sigmoidf_(a[j][2] * 0.125f + bl2) * wsl2 +
                          sigmoidf_(a[j][3] * 0.125f + bl3) * wsl3;
                unsigned u = __float_as_uint(s);
                key = (u & 0x80000000u) ? ~u : (u | 0x80000000u);
            }
            ks_[k] = key;
        }
    }
    __syncthreads();
    if (n <= KSEL) {
        if (tid < n) indices[qrow * KSEL + tid] = tid;
        if (tid == 0) counts[qrow] = n;
        return;
    }
    if (tid == 0) counts[qrow] = KSEL;
    // ---- radix select: find threshold key T (count(>T) < K <= count(>=T))
    unsigned prefix = 0;
    int remaining = KSEL;
    for (int level = 24; level >= 0; level -= 8) {
        hist[tid] = 0;
        __syncthreads();
        for (int k = tid; k < TT; k += 256) {
            unsigned key = ks_[k];
            bool match = ((unsigned long long)key >> (level + 8)) == (unsigned long long)prefix;
            if (match) atomicAdd(&hist[(key >> level) & 255], 1u);
        }
        __syncthreads();
        // suffix sum: hist[b] = count of matched keys in buckets >= b
#pragma unroll
        for (int off = 1; off < 256; off <<= 1) {
            unsigned vv = (tid + off < 256) ? hist[tid + off] : 0u;
            __syncthreads();
            hist[tid] += vv;
            __syncthreads();
        }
        // boundary: largest b with suffix[b] >= remaining (exactly one thread)
        if (hist[tid] >= (unsigned)remaining &&
            (tid == 255 || hist[tid + 1] < (unsigned)remaining)) {
            s_prefix = (prefix << 8) | (unsigned)tid;
            s_above = (tid == 255) ? 0u : hist[tid + 1];
        }
        __syncthreads();
        prefix = s_prefix;
        remaining -= (int)s_above;
        __syncthreads();
    }
    // prefix == exact 32-bit threshold key T; remaining r >= 1 taken from ==T
    if (tid == 0) { eqcount = 0; outpos = 0; }
    __syncthreads();
    int outbase = qrow * KSEL;
    for (int k = tid; k < TT; k += 256) {
        unsigned key = ks_[k];
        if (key > prefix) {
            unsigned p = atomicAdd(&outpos, 1u);
            indices[outbase + p] = k;
        } else if (key == prefix) {
            unsigned e = atomicAdd(&eqcount, 1u);
            if (e < 256) eqlist[e] = k;
        }
    }
    __syncthreads();
    if (tid == 0) {
        int r = remaining;
        int E = (int)eqcount;
        if (E > 256) E = 256;
        if (r > E) r = E;
        int pos = (int)outpos;
        for (int t = 0; t < r; ++t) {
            int best = 0x7fffffff, bj = -1;
            for (int j = 0; j < E; ++j) {
                int vv = eqlist[j];
                if (vv < best) { best = vv; bj = j; }
            }
            eqlist[bj] = 0x7fffffff;
            indices[outbase + pos + t] = best;
        }
    }
}

// ---------------------------------------------------------------------------
// Sparse attention over selected keys + og gate. One block per query row.
// K staged in LDS (float4 loads); P*V accumulated straight from global with
// wave-coalesced reads (4 waves partition the key range).
// ---------------------------------------------------------------------------
__global__ __launch_bounds__(256) void attn_kernel(
    const float* __restrict__ q, const float* __restrict__ k,
    const float* __restrict__ v, const float* __restrict__ og,
    const int* __restrict__ indices, const int* __restrict__ counts,
    float* __restrict__ out) {
    __shared__ float kt[KSEL * 65];
    __shared__ float qv[DH];
    __shared__ float pp[KSEL];
    __shared__ int idx[KSEL];
    __shared__ float red[2];
    __shared__ float partial[4][64];
    int qrow = blockIdx.x;
    int tid = threadIdx.x;
    int cnt = counts[qrow];
    if (tid < KSEL) idx[tid] = (tid < cnt) ? indices[qrow * KSEL + tid] : 0;
    __syncthreads();
    for (int h = 0; h < HEADS; ++h) {
        if (tid < DH) qv[tid] = q[qrow * DD + h * DH + tid];
        for (int e = tid; e < cnt * 16; e += 256) {
            int s = e >> 4, c = e & 15;
            float4 kv = *(const float4*)(k + (size_t)idx[s] * DD + h * DH + c * 4);
            int a = s * 65 + c * 4;
            kt[a] = kv.x; kt[a + 1] = kv.y; kt[a + 2] = kv.z; kt[a + 3] = kv.w;
        }
        __syncthreads();
        if (tid < KSEL) {
            float sval = -1e30f;
            if (tid < cnt) {
                float acc = 0.f;
#pragma unroll 8
                for (int d = 0; d < DH; ++d) acc += qv[d] * kt[tid * 65 + d];
                sval = acc * 0.125f;
            }
            pp[tid] = sval;
        }
        __syncthreads();
        if (tid < 64) {
            float m = fmaxf(pp[tid], pp[tid + 64]);
#pragma unroll
            for (int off = 32; off; off >>= 1) m = fmaxf(m, __shfl_down(m, off));
            if (tid == 0) red[0] = m;
        }
        __syncthreads();
        float mx = red[0];
        if (tid < KSEL) pp[tid] = (tid < cnt) ? __expf(pp[tid] - mx) : 0.0f;
        __syncthreads();
        if (tid < 64) {
            float s = pp[tid] + pp[tid + 64];
#pragma unroll
            for (int off = 32; off; off >>= 1) s += __shfl_down(s, off);
            if (tid == 0) red[1] = s;
        }
        __syncthreads();
        float inv = 1.0f / red[1];
        {
            int d = tid & 63, part = tid >> 6;
            float acc = 0.f;
            for (int j = part; j < cnt; j += 4)
                acc += pp[j] * v[(size_t)idx[j] * DD + h * DH + d];
            partial[part][d] = acc;
        }
        __syncthreads();
        if (tid < DH) {
            float s = (partial[0][tid] + partial[1][tid]) +
                      (partial[2][tid] + partial[3][tid]);
            int o = qrow * DD + h * DH + tid;
            out[o] = s * inv * og[o];
        }
        __syncthreads();
    }
}

// ---------------------------------------------------------------------------
extern "C" void kernel_launch(void* const* d_in, const int* in_sizes, int n_in,
                              void* d_out, int out_size, void* d_ws, size_t ws_size,
                              hipStream_t stream) {
    const float* x = (const float*)d_in[0];
    const float* Wq = (const float*)d_in[1];
    const float* Wk = (const float*)d_in[2];
    const float* Wv = (const float*)d_in[3];
    const float* Wo = (const float*)d_in[4];
    const float* Wiq = (const float*)d_in[5];
    const float* Wik = (const float*)d_in[6];
    const float* Wiw = (const float*)d_in[7];
    const float* biw = (const float*)d_in[8];
    const float* idx_bias = (const float*)d_in[9];
    const float* Wvg = (const float*)d_in[10];
    const float* bvg = (const float*)d_in[11];
    const float* Wog = (const float*)d_in[12];
    const float* bog = (const float*)d_in[13];
    float* out = (float*)d_out;
    float* ws = (float*)d_ws;

    float* qb = ws;
    float* kb = ws + (1 << 20);
    float* vb = ws + (2 << 20);
    float* vgb = ws + (3 << 20);
    float* ogb = ws + (4 << 20);
    float* qib = ws + (5 << 20);
    float* kib = qib + TT * NI * DI;
    float* wsb = kib + TT * DI;
    float* ab = ws + (6 << 20);
    int* idxb = (int*)(ws + (7 << 20));
    int* cntb = idxb + TT * KSEL;

    dim3 blk(256);
    gemm64<0><<<dim3(8, 32), blk, 0, stream>>>(x, Wq, nullptr, qb, TT, DD, DD);
    gemm64<0><<<dim3(8, 32), blk, 0, stream>>>(x, Wk, nullptr, kb, TT, DD, DD);
    gemm64<0><<<dim3(8, 32), blk, 0, stream>>>(x, Wv, nullptr, vb, TT, DD, DD);
    gemm64<1><<<dim3(8, 32), blk, 0, stream>>>(x, Wvg, bvg, vgb, TT, DD, DD);
    gemm64<1><<<dim3(8, 32), blk, 0, stream>>>(x, Wog, bog, ogb, TT, DD, DD);
    gemm64<0><<<dim3(4, 32), blk, 0, stream>>>(x, Wiq, nullptr, qib, TT, NI * DI, DD);
    gemm64<0><<<dim3(1, 32), blk, 0, stream>>>(x, Wik, nullptr, kib, TT, DI, DD);
    iw_kernel<<<TT, blk, 0, stream>>>(x, Wiw, biw, wsb);
    vmul_kernel<<<(TT * DD) / 256, blk, 0, stream>>>(vb, vgb);
    rope_kernel<<<(TT * HEADS * 32) / 256, blk, 0, stream>>>(qb, kb);
    score_topk_kernel<<<TT, blk, 0, stream>>>(qib, kib, wsb, idx_bias, idxb, cntb);
    attn_kernel<<<TT, blk, 0, stream>>>(qb, kb, vb, ogb, idxb, cntb, ab);
    gemm64<0><<<dim3(8, 32), blk, 0, stream>>>(ab, Wo, nullptr, out, TT, DD, DD);
}

// Round 3
// 615.202 us; speedup vs baseline: 1.3409x; 1.2771x over previous
//
#include <hip/hip_runtime.h>
#include <math.h>

#define TT 2048
#define DD 512
#define HEADS 8
#define DH 64
#define NI 4
#define DI 64
#define KSEL 128

__device__ __forceinline__ float sigmoidf_(float z) {
    return 1.0f / (1.0f + __expf(-z));
}

// ---------------------------------------------------------------------------
// Tiled fp32 GEMM: C[M,N] = A[M,K] @ B[K,N]; EPI==1: C = sigmoid(acc + bias[n])
// ---------------------------------------------------------------------------
template <int EPI>
__global__ __launch_bounds__(256) void gemm64(const float* __restrict__ A,
                                              const float* __restrict__ B,
                                              const float* __restrict__ bias,
                                              float* __restrict__ C,
                                              int M, int N, int K) {
    __shared__ float As[64][17];
    __shared__ float Bs[16][64];
    int tid = threadIdx.x;
    int bm = blockIdx.y * 64;
    int bn = blockIdx.x * 64;
    int tx = tid & 15, ty = tid >> 4;
    float acc[4][4] = {};
    for (int k0 = 0; k0 < K; k0 += 16) {
#pragma unroll
        for (int i = 0; i < 4; ++i) {
            int e = tid + i * 256;
            int m = e >> 4, kk = e & 15;
            As[m][kk] = A[(size_t)(bm + m) * K + k0 + kk];
        }
#pragma unroll
        for (int i = 0; i < 4; ++i) {
            int e = tid + i * 256;
            int kk = e >> 6, n = e & 63;
            Bs[kk][n] = B[(size_t)(k0 + kk) * N + bn + n];
        }
        __syncthreads();
#pragma unroll
        for (int kk = 0; kk < 16; ++kk) {
            float a[4], b[4];
#pragma unroll
            for (int i = 0; i < 4; ++i) a[i] = As[ty * 4 + i][kk];
#pragma unroll
            for (int j = 0; j < 4; ++j) b[j] = Bs[kk][tx * 4 + j];
#pragma unroll
            for (int i = 0; i < 4; ++i)
#pragma unroll
                for (int j = 0; j < 4; ++j) acc[i][j] += a[i] * b[j];
        }
        __syncthreads();
    }
#pragma unroll
    for (int i = 0; i < 4; ++i) {
        int m = bm + ty * 4 + i;
#pragma unroll
        for (int j = 0; j < 4; ++j) {
            int n = bn + tx * 4 + j;
            float v = acc[i][j];
            if (EPI == 1) v = sigmoidf_(v + bias[n]);
            C[(size_t)m * N + n] = v;
        }
    }
}

__global__ __launch_bounds__(256) void iw_kernel(const float* __restrict__ x,
                                                 const float* __restrict__ Wiw,
                                                 const float* __restrict__ biw,
                                                 float* __restrict__ wsig) {
    int t = blockIdx.x;
    int tid = threadIdx.x;
    int lane = tid & 63, c = tid >> 6;
    float acc = 0.f;
    for (int k = lane; k < DD; k += 64) acc += x[t * DD + k] * Wiw[k * NI + c];
#pragma unroll
    for (int off = 32; off; off >>= 1) acc += __shfl_down(acc, off);
    if (lane == 0) wsig[t * NI + c] = sigmoidf_(acc + biw[c]);
}

__global__ void vmul_kernel(float* __restrict__ v, const float* __restrict__ vg) {
    int i = blockIdx.x * blockDim.x + threadIdx.x;
    v[i] *= vg[i];
}

__global__ void rope_kernel(float* __restrict__ q, float* __restrict__ k) {
    int i = blockIdx.x * blockDim.x + threadIdx.x;
    int j = i & 31;
    int h = (i >> 5) & 7;
    int t = i >> 8;
    if (t >= TT) return;
    const float L2_10000 = 13.287712379549449f;
    float inv = exp2f(-(float)j * (1.0f / 32.0f) * L2_10000);
    float ang = (float)t * inv;
    float c = cosf(ang), s = sinf(ang);
    int base = t * DD + h * DH;
    float q1 = q[base + j], q2 = q[base + j + 32];
    q[base + j] = q1 * c - q2 * s;
    q[base + j + 32] = q2 * c + q1 * s;
    float k1 = k[base + j], k2 = k[base + j + 32];
    k[base + j] = k1 * c - k2 * s;
    k[base + j + 32] = k2 * c + k1 * s;
}

// ---------------------------------------------------------------------------
// Combined index-score GEMM over lower-triangle 64x64 tiles.
// keys[q*TT+k] = monotone-uint of sum_h sigmoid(qi.ki/8 + b_h)*wsig[q,h],
// 0 for k>q (causal). Heads looped sequentially to keep VGPR low.
// ---------------------------------------------------------------------------
__global__ __launch_bounds__(256) void score_kernel(
    const float* __restrict__ qi, const float* __restrict__ ki,
    const float* __restrict__ wsig, const float* __restrict__ idx_bias,
    unsigned* __restrict__ keys) {
    __shared__ float As[64][65];  // q-rows x d (head slice)
    __shared__ float Bs[64][65];  // d x k-cols (ki transposed)
    int b = blockIdx.x;
    int bq = (int)((sqrtf(8.0f * (float)b + 1.0f) - 1.0f) * 0.5f);
    while ((bq + 1) * (bq + 2) / 2 <= b) ++bq;
    while (bq * (bq + 1) / 2 > b) --bq;
    int bk = b - bq * (bq + 1) / 2;
    int q0 = bq * 64, k0 = bk * 64;
    int tid = threadIdx.x;
    int tx = tid & 15, ty = tid >> 4;
    float fin[4][4] = {};
#pragma unroll
    for (int h = 0; h < NI; ++h) {
#pragma unroll
        for (int i = 0; i < 4; ++i) {
            int e = tid + i * 256;  // [0,1024): r = e>>4, c4 = e&15
            int r = e >> 4, c4 = e & 15;
            float4 av = *(const float4*)(qi + (size_t)(q0 + r) * (NI * DI) + h * DI + c4 * 4);
            As[r][c4 * 4 + 0] = av.x;
            As[r][c4 * 4 + 1] = av.y;
            As[r][c4 * 4 + 2] = av.z;
            As[r][c4 * 4 + 3] = av.w;
            float4 bv = *(const float4*)(ki + (size_t)(k0 + r) * DI + c4 * 4);
            Bs[c4 * 4 + 0][r] = bv.x;
            Bs[c4 * 4 + 1][r] = bv.y;
            Bs[c4 * 4 + 2][r] = bv.z;
            Bs[c4 * 4 + 3][r] = bv.w;
        }
        __syncthreads();
        float raw[4][4] = {};
#pragma unroll 8
        for (int kk = 0; kk < 64; ++kk) {
            float a[4], bb[4];
#pragma unroll
            for (int i = 0; i < 4; ++i) a[i] = As[ty * 4 + i][kk];
#pragma unroll
            for (int j = 0; j < 4; ++j) bb[j] = Bs[kk][tx * 4 + j];
#pragma unroll
            for (int i = 0; i < 4; ++i)
#pragma unroll
                for (int j = 0; j < 4; ++j) raw[i][j] += a[i] * bb[j];
        }
        float bh = idx_bias[h];
        float w4[4];
#pragma unroll
        for (int i = 0; i < 4; ++i) w4[i] = wsig[(q0 + ty * 4 + i) * NI + h];
#pragma unroll
        for (int i = 0; i < 4; ++i)
#pragma unroll
            for (int j = 0; j < 4; ++j)
                fin[i][j] += sigmoidf_(raw[i][j] * 0.125f + bh) * w4[i];
        __syncthreads();
    }
#pragma unroll
    for (int i = 0; i < 4; ++i) {
        int qq = q0 + ty * 4 + i;
#pragma unroll
        for (int j = 0; j < 4; ++j) {
            int kk = k0 + tx * 4 + j;
            unsigned key = 0;
            if (kk <= qq) {
                unsigned u = __float_as_uint(fin[i][j]);
                key = (u & 0x80000000u) ? ~u : (u | 0x80000000u);
            }
            keys[(size_t)qq * TT + kk] = key;
        }
    }
}

// ---------------------------------------------------------------------------
// Exact top-K per row via MSB-first radix select on precomputed keys.
// One block of 256 threads per query row. Ties -> lowest index.
// ---------------------------------------------------------------------------
__global__ __launch_bounds__(256) void topk_kernel(
    const unsigned* __restrict__ keys, int* __restrict__ indices,
    int* __restrict__ counts) {
    __shared__ unsigned ks_[TT];
    __shared__ unsigned hist[256];
    __shared__ unsigned s_prefix, s_above;
    __shared__ int eqlist[256];
    __shared__ unsigned eqcount, outpos;
    int qrow = blockIdx.x;
    int tid = threadIdx.x;
    int n = qrow + 1;
    if (n <= KSEL) {
        if (tid < n) indices[qrow * KSEL + tid] = tid;
        if (tid == 0) counts[qrow] = n;
        return;
    }
    if (tid == 0) counts[qrow] = KSEL;
    const unsigned* krow = keys + (size_t)qrow * TT;
    for (int k = tid; k < n; k += 256) ks_[k] = krow[k];
    __syncthreads();
    unsigned prefix = 0;
    int remaining = KSEL;
    for (int level = 24; level >= 0; level -= 8) {
        hist[tid] = 0;
        __syncthreads();
        for (int k = tid; k < n; k += 256) {
            unsigned key = ks_[k];
            bool match = ((unsigned long long)key >> (level + 8)) == (unsigned long long)prefix;
            if (match) atomicAdd(&hist[(key >> level) & 255], 1u);
        }
        __syncthreads();
#pragma unroll
        for (int off = 1; off < 256; off <<= 1) {
            unsigned vv = (tid + off < 256) ? hist[tid + off] : 0u;
            __syncthreads();
            hist[tid] += vv;
            __syncthreads();
        }
        if (hist[tid] >= (unsigned)remaining &&
            (tid == 255 || hist[tid + 1] < (unsigned)remaining)) {
            s_prefix = (prefix << 8) | (unsigned)tid;
            s_above = (tid == 255) ? 0u : hist[tid + 1];
        }
        __syncthreads();
        prefix = s_prefix;
        remaining -= (int)s_above;
        __syncthreads();
    }
    if (tid == 0) { eqcount = 0; outpos = 0; }
    __syncthreads();
    int outbase = qrow * KSEL;
    for (int k = tid; k < n; k += 256) {
        unsigned key = ks_[k];
        if (key > prefix) {
            unsigned p = atomicAdd(&outpos, 1u);
            indices[outbase + p] = k;
        } else if (key == prefix) {
            unsigned e = atomicAdd(&eqcount, 1u);
            if (e < 256) eqlist[e] = k;
        }
    }
    __syncthreads();
    if (tid == 0) {
        int r = remaining;
        int E = (int)eqcount;
        if (E > 256) E = 256;
        if (r > E) r = E;
        int pos = (int)outpos;
        for (int t = 0; t < r; ++t) {
            int best = 0x7fffffff, bj = -1;
            for (int j = 0; j < E; ++j) {
                int vv = eqlist[j];
                if (vv < best) { best = vv; bj = j; }
            }
            eqlist[bj] = 0x7fffffff;
            indices[outbase + pos + t] = best;
        }
    }
}

// ---------------------------------------------------------------------------
// Sparse attention over selected keys + og gate. One block per query row.
// ---------------------------------------------------------------------------
__global__ __launch_bounds__(256) void attn_kernel(
    const float* __restrict__ q, const float* __restrict__ k,
    const float* __restrict__ v, const float* __restrict__ og,
    const int* __restrict__ indices, const int* __restrict__ counts,
    float* __restrict__ out) {
    __shared__ float kt[KSEL * 65];
    __shared__ float qv[DH];
    __shared__ float pp[KSEL];
    __shared__ int idx[KSEL];
    __shared__ float red[2];
    __shared__ float partial[4][64];
    int qrow = blockIdx.x;
    int tid = threadIdx.x;
    int cnt = counts[qrow];
    if (tid < KSEL) idx[tid] = (tid < cnt) ? indices[qrow * KSEL + tid] : 0;
    __syncthreads();
    for (int h = 0; h < HEADS; ++h) {
        if (tid < DH) qv[tid] = q[qrow * DD + h * DH + tid];
        for (int e = tid; e < cnt * 16; e += 256) {
            int s = e >> 4, c = e & 15;
            float4 kv = *(const float4*)(k + (size_t)idx[s] * DD + h * DH + c * 4);
            int a = s * 65 + c * 4;
            kt[a] = kv.x; kt[a + 1] = kv.y; kt[a + 2] = kv.z; kt[a + 3] = kv.w;
        }
        __syncthreads();
        if (tid < KSEL) {
            float sval = -1e30f;
            if (tid < cnt) {
                float acc = 0.f;
#pragma unroll 8
                for (int d = 0; d < DH; ++d) acc += qv[d] * kt[tid * 65 + d];
                sval = acc * 0.125f;
            }
            pp[tid] = sval;
        }
        __syncthreads();
        if (tid < 64) {
            float m = fmaxf(pp[tid], pp[tid + 64]);
#pragma unroll
            for (int off = 32; off; off >>= 1) m = fmaxf(m, __shfl_down(m, off));
            if (tid == 0) red[0] = m;
        }
        __syncthreads();
        float mx = red[0];
        if (tid < KSEL) pp[tid] = (tid < cnt) ? __expf(pp[tid] - mx) : 0.0f;
        __syncthreads();
        if (tid < 64) {
            float s = pp[tid] + pp[tid + 64];
#pragma unroll
            for (int off = 32; off; off >>= 1) s += __shfl_down(s, off);
            if (tid == 0) red[1] = s;
        }
        __syncthreads();
        float inv = 1.0f / red[1];
        {
            int d = tid & 63, part = tid >> 6;
            float acc = 0.f;
            for (int j = part; j < cnt; j += 4)
                acc += pp[j] * v[(size_t)idx[j] * DD + h * DH + d];
            partial[part][d] = acc;
        }
        __syncthreads();
        if (tid < DH) {
            float s = (partial[0][tid] + partial[1][tid]) +
                      (partial[2][tid] + partial[3][tid]);
            int o = qrow * DD + h * DH + tid;
            out[o] = s * inv * og[o];
        }
        __syncthreads();
    }
}

// ---------------------------------------------------------------------------
extern "C" void kernel_launch(void* const* d_in, const int* in_sizes, int n_in,
                              void* d_out, int out_size, void* d_ws, size_t ws_size,
                              hipStream_t stream) {
    const float* x = (const float*)d_in[0];
    const float* Wq = (const float*)d_in[1];
    const float* Wk = (const float*)d_in[2];
    const float* Wv = (const float*)d_in[3];
    const float* Wo = (const float*)d_in[4];
    const float* Wiq = (const float*)d_in[5];
    const float* Wik = (const float*)d_in[6];
    const float* Wiw = (const float*)d_in[7];
    const float* biw = (const float*)d_in[8];
    const float* idx_bias = (const float*)d_in[9];
    const float* Wvg = (const float*)d_in[10];
    const float* bvg = (const float*)d_in[11];
    const float* Wog = (const float*)d_in[12];
    const float* bog = (const float*)d_in[13];
    float* out = (float*)d_out;
    float* ws = (float*)d_ws;

    float* qb = ws;                      // 1M floats each slot
    float* kb = ws + (1 << 20);
    float* vb = ws + (2 << 20);
    float* vgb = ws + (3 << 20);
    float* ogb = ws + (4 << 20);
    float* qib = ws + (5 << 20);
    float* kib = qib + TT * NI * DI;
    float* wsb = kib + TT * DI;
    float* ab = ws + (6 << 20);
    int* idxb = (int*)(ws + (7 << 20));
    int* cntb = idxb + TT * KSEL;
    unsigned* keysb = (unsigned*)(ws + (8 << 20));  // TT*TT uints = 16.8 MB

    dim3 blk(256);
    gemm64<0><<<dim3(8, 32), blk, 0, stream>>>(x, Wq, nullptr, qb, TT, DD, DD);
    gemm64<0><<<dim3(8, 32), blk, 0, stream>>>(x, Wk, nullptr, kb, TT, DD, DD);
    gemm64<0><<<dim3(8, 32), blk, 0, stream>>>(x, Wv, nullptr, vb, TT, DD, DD);
    gemm64<1><<<dim3(8, 32), blk, 0, stream>>>(x, Wvg, bvg, vgb, TT, DD, DD);
    gemm64<1><<<dim3(8, 32), blk, 0, stream>>>(x, Wog, bog, ogb, TT, DD, DD);
    gemm64<0><<<dim3(4, 32), blk, 0, stream>>>(x, Wiq, nullptr, qib, TT, NI * DI, DD);
    gemm64<0><<<dim3(1, 32), blk, 0, stream>>>(x, Wik, nullptr, kib, TT, DI, DD);
    iw_kernel<<<TT, blk, 0, stream>>>(x, Wiw, biw, wsb);
    vmul_kernel<<<(TT * DD) / 256, blk, 0, stream>>>(vb, vgb);
    rope_kernel<<<(TT * HEADS * 32) / 256, blk, 0, stream>>>(qb, kb);
    score_kernel<<<528, blk, 0, stream>>>(qib, kib, wsb, idx_bias, keysb);
    topk_kernel<<<TT, blk, 0, stream>>>(keysb, idxb, cntb);
    attn_kernel<<<TT, blk, 0, stream>>>(qb, kb, vb, ogb, idxb, cntb, ab);
    gemm64<0><<<dim3(8, 32), blk, 0, stream>>>(ab, Wo, nullptr, out, TT, DD, DD);
}

// Round 4
// 364.341 us; speedup vs baseline: 2.2641x; 1.6885x over previous
//
#include <hip/hip_runtime.h>
#include <math.h>

#define TT 2048
#define DD 512
#define HEADS 8
#define DH 64
#define NI 4
#define DI 64
#define KSEL 128

__device__ __forceinline__ float sigmoidf_(float z) {
    return 1.0f / (1.0f + __expf(-z));
}

// ---------------------------------------------------------------------------
// 64x64 fp32 GEMM tile, A staged transposed so both fragments read as b128.
// 256 threads, 4x4 micro-tile. epi==1: C = sigmoid(acc + bias[col]).
// ---------------------------------------------------------------------------
__device__ __forceinline__ void gemm_tile64(const float* __restrict__ A,
                                            const float* __restrict__ B,
                                            const float* __restrict__ bias,
                                            float* __restrict__ C,
                                            int N, int K, int bm, int bn0,
                                            int epi) {
    __shared__ float Ast[16][64];  // [k][m]
    __shared__ float Bs[16][64];   // [k][n]
    int tid = threadIdx.x;
    int tx = tid & 15, ty = tid >> 4;
    int ma = tid >> 2, kq = tid & 3;
    int kb_ = tid >> 4, n4 = tid & 15;
    float acc[4][4] = {};
    for (int k0 = 0; k0 < K; k0 += 16) {
        float4 av = *(const float4*)(A + (size_t)(bm + ma) * K + k0 + kq * 4);
        *(float4*)&Bs[kb_][n4 * 4] =
            *(const float4*)(B + (size_t)(k0 + kb_) * N + bn0 + n4 * 4);
        Ast[kq * 4 + 0][ma] = av.x;
        Ast[kq * 4 + 1][ma] = av.y;
        Ast[kq * 4 + 2][ma] = av.z;
        Ast[kq * 4 + 3][ma] = av.w;
        __syncthreads();
#pragma unroll
        for (int kk = 0; kk < 16; ++kk) {
            float4 a4 = *(const float4*)&Ast[kk][ty * 4];
            float4 b4 = *(const float4*)&Bs[kk][tx * 4];
            float af[4] = {a4.x, a4.y, a4.z, a4.w};
            float bf[4] = {b4.x, b4.y, b4.z, b4.w};
#pragma unroll
            for (int i = 0; i < 4; ++i)
#pragma unroll
                for (int j = 0; j < 4; ++j) acc[i][j] += af[i] * bf[j];
        }
        __syncthreads();
    }
#pragma unroll
    for (int i = 0; i < 4; ++i) {
        int mrow = bm + ty * 4 + i;
#pragma unroll
        for (int j = 0; j < 4; ++j) {
            int ncol = bn0 + tx * 4 + j;
            float vv = acc[i][j];
            if (epi) vv = sigmoidf_(vv + bias[ncol]);
            C[(size_t)mrow * N + ncol] = vv;
        }
    }
}

// All 7 projections in one launch. blockIdx.x routes to a matrix.
__global__ __launch_bounds__(256) void proj_kernel(
    const float* __restrict__ x, const float* __restrict__ Wq,
    const float* __restrict__ Wk, const float* __restrict__ Wv,
    const float* __restrict__ Wvg, const float* __restrict__ Wog,
    const float* __restrict__ Wiq, const float* __restrict__ Wik,
    const float* __restrict__ bvg, const float* __restrict__ bog,
    float* __restrict__ qb, float* __restrict__ kb, float* __restrict__ vb,
    float* __restrict__ vgb, float* __restrict__ ogb, float* __restrict__ qib,
    float* __restrict__ kib) {
    int bn = blockIdx.x, bm = blockIdx.y * 64;
    const float *B, *bias = nullptr;
    float* C;
    int N, bn0, epi = 0;
    if (bn < 8) { B = Wq; C = qb; N = 512; bn0 = bn * 64; }
    else if (bn < 16) { B = Wk; C = kb; N = 512; bn0 = (bn - 8) * 64; }
    else if (bn < 24) { B = Wv; C = vb; N = 512; bn0 = (bn - 16) * 64; }
    else if (bn < 32) { B = Wvg; C = vgb; N = 512; bn0 = (bn - 24) * 64; epi = 1; bias = bvg; }
    else if (bn < 40) { B = Wog; C = ogb; N = 512; bn0 = (bn - 32) * 64; epi = 1; bias = bog; }
    else if (bn < 44) { B = Wiq; C = qib; N = 256; bn0 = (bn - 40) * 64; }
    else { B = Wik; C = kib; N = 64; bn0 = 0; }
    gemm_tile64(x, B, bias, C, N, 512, bm, bn0, epi);
}

__global__ __launch_bounds__(256) void wo_kernel(const float* __restrict__ A,
                                                 const float* __restrict__ B,
                                                 float* __restrict__ C) {
    gemm_tile64(A, B, nullptr, C, 512, 512, blockIdx.y * 64, blockIdx.x * 64, 0);
}

__global__ __launch_bounds__(256) void iw_kernel(const float* __restrict__ x,
                                                 const float* __restrict__ Wiw,
                                                 const float* __restrict__ biw,
                                                 float* __restrict__ wsig) {
    int t = blockIdx.x;
    int tid = threadIdx.x;
    int lane = tid & 63, c = tid >> 6;
    float acc = 0.f;
    for (int k = lane; k < DD; k += 64) acc += x[t * DD + k] * Wiw[k * NI + c];
#pragma unroll
    for (int off = 32; off; off >>= 1) acc += __shfl_down(acc, off);
    if (lane == 0) wsig[t * NI + c] = sigmoidf_(acc + biw[c]);
}

__global__ void vmul_kernel(float* __restrict__ v, const float* __restrict__ vg) {
    int i = blockIdx.x * blockDim.x + threadIdx.x;
    v[i] *= vg[i];
}

__global__ void rope_kernel(float* __restrict__ q, float* __restrict__ k) {
    int i = blockIdx.x * blockDim.x + threadIdx.x;
    int j = i & 31;
    int h = (i >> 5) & 7;
    int t = i >> 8;
    if (t >= TT) return;
    const float L2_10000 = 13.287712379549449f;
    float inv = exp2f(-(float)j * (1.0f / 32.0f) * L2_10000);
    float ang = (float)t * inv;
    float c = cosf(ang), s = sinf(ang);
    int base = t * DD + h * DH;
    float q1 = q[base + j], q2 = q[base + j + 32];
    q[base + j] = q1 * c - q2 * s;
    q[base + j + 32] = q2 * c + q1 * s;
    float k1 = k[base + j], k2 = k[base + j + 32];
    k[base + j] = k1 * c - k2 * s;
    k[base + j + 32] = k2 * c + k1 * s;
}

// ---------------------------------------------------------------------------
// Index-score GEMM over lower-triangle 64x64 tiles -> monotone uint keys.
// ---------------------------------------------------------------------------
__global__ __launch_bounds__(256) void score_kernel(
    const float* __restrict__ qi, const float* __restrict__ ki,
    const float* __restrict__ wsig, const float* __restrict__ idx_bias,
    unsigned* __restrict__ keys) {
    __shared__ float As[64][65];
    __shared__ float Bs[64][65];
    int b = blockIdx.x;
    int bq = (int)((sqrtf(8.0f * (float)b + 1.0f) - 1.0f) * 0.5f);
    while ((bq + 1) * (bq + 2) / 2 <= b) ++bq;
    while (bq * (bq + 1) / 2 > b) --bq;
    int bk = b - bq * (bq + 1) / 2;
    int q0 = bq * 64, k0 = bk * 64;
    int tid = threadIdx.x;
    int tx = tid & 15, ty = tid >> 4;
    float fin[4][4] = {};
#pragma unroll
    for (int h = 0; h < NI; ++h) {
#pragma unroll
        for (int i = 0; i < 4; ++i) {
            int e = tid + i * 256;
            int r = e >> 4, c4 = e & 15;
            float4 av = *(const float4*)(qi + (size_t)(q0 + r) * (NI * DI) + h * DI + c4 * 4);
            As[r][c4 * 4 + 0] = av.x;
            As[r][c4 * 4 + 1] = av.y;
            As[r][c4 * 4 + 2] = av.z;
            As[r][c4 * 4 + 3] = av.w;
            float4 bv = *(const float4*)(ki + (size_t)(k0 + r) * DI + c4 * 4);
            Bs[c4 * 4 + 0][r] = bv.x;
            Bs[c4 * 4 + 1][r] = bv.y;
            Bs[c4 * 4 + 2][r] = bv.z;
            Bs[c4 * 4 + 3][r] = bv.w;
        }
        __syncthreads();
        float raw[4][4] = {};
#pragma unroll 8
        for (int kk = 0; kk < 64; ++kk) {
            float a[4], bb[4];
#pragma unroll
            for (int i = 0; i < 4; ++i) a[i] = As[ty * 4 + i][kk];
#pragma unroll
            for (int j = 0; j < 4; ++j) bb[j] = Bs[kk][tx * 4 + j];
#pragma unroll
            for (int i = 0; i < 4; ++i)
#pragma unroll
                for (int j = 0; j < 4; ++j) raw[i][j] += a[i] * bb[j];
        }
        float bh = idx_bias[h];
        float w4[4];
#pragma unroll
        for (int i = 0; i < 4; ++i) w4[i] = wsig[(q0 + ty * 4 + i) * NI + h];
#pragma unroll
        for (int i = 0; i < 4; ++i)
#pragma unroll
            for (int j = 0; j < 4; ++j)
                fin[i][j] += sigmoidf_(raw[i][j] * 0.125f + bh) * w4[i];
        __syncthreads();
    }
#pragma unroll
    for (int i = 0; i < 4; ++i) {
        int qq = q0 + ty * 4 + i;
#pragma unroll
        for (int j = 0; j < 4; ++j) {
            int kk = k0 + tx * 4 + j;
            unsigned key = 0;
            if (kk <= qq) {
                unsigned u = __float_as_uint(fin[i][j]);
                key = (u & 0x80000000u) ? ~u : (u | 0x80000000u);
            }
            keys[(size_t)qq * TT + kk] = key;
        }
    }
}

// ---------------------------------------------------------------------------
// Exact per-row top-K via MSB-first radix select. Ties -> lowest index.
// ---------------------------------------------------------------------------
__global__ __launch_bounds__(256) void topk_kernel(
    const unsigned* __restrict__ keys, int* __restrict__ indices,
    int* __restrict__ counts) {
    __shared__ unsigned ks_[TT];
    __shared__ unsigned hist[256];
    __shared__ unsigned s_prefix, s_above;
    __shared__ int eqlist[256];
    __shared__ unsigned eqcount, outpos;
    int qrow = blockIdx.x;
    int tid = threadIdx.x;
    int n = qrow + 1;
    if (n <= KSEL) {
        if (tid < n) indices[qrow * KSEL + tid] = tid;
        if (tid == 0) counts[qrow] = n;
        return;
    }
    if (tid == 0) counts[qrow] = KSEL;
    const unsigned* krow = keys + (size_t)qrow * TT;
    for (int k = tid; k < n; k += 256) ks_[k] = krow[k];
    __syncthreads();
    unsigned prefix = 0;
    int remaining = KSEL;
    for (int level = 24; level >= 0; level -= 8) {
        hist[tid] = 0;
        __syncthreads();
        for (int k = tid; k < n; k += 256) {
            unsigned key = ks_[k];
            bool match = ((unsigned long long)key >> (level + 8)) == (unsigned long long)prefix;
            if (match) atomicAdd(&hist[(key >> level) & 255], 1u);
        }
        __syncthreads();
#pragma unroll
        for (int off = 1; off < 256; off <<= 1) {
            unsigned vv = (tid + off < 256) ? hist[tid + off] : 0u;
            __syncthreads();
            hist[tid] += vv;
            __syncthreads();
        }
        if (hist[tid] >= (unsigned)remaining &&
            (tid == 255 || hist[tid + 1] < (unsigned)remaining)) {
            s_prefix = (prefix << 8) | (unsigned)tid;
            s_above = (tid == 255) ? 0u : hist[tid + 1];
        }
        __syncthreads();
        prefix = s_prefix;
        remaining -= (int)s_above;
        __syncthreads();
    }
    if (tid == 0) { eqcount = 0; outpos = 0; }
    __syncthreads();
    int outbase = qrow * KSEL;
    for (int k = tid; k < n; k += 256) {
        unsigned key = ks_[k];
        if (key > prefix) {
            unsigned p = atomicAdd(&outpos, 1u);
            indices[outbase + p] = k;
        } else if (key == prefix) {
            unsigned e = atomicAdd(&eqcount, 1u);
            if (e < 256) eqlist[e] = k;
        }
    }
    __syncthreads();
    if (tid == 0) {
        int r = remaining;
        int E = (int)eqcount;
        if (E > 256) E = 256;
        if (r > E) r = E;
        int pos = (int)outpos;
        for (int t = 0; t < r; ++t) {
            int best = 0x7fffffff, bj = -1;
            for (int j = 0; j < E; ++j) {
                int vv = eqlist[j];
                if (vv < best) { best = vv; bj = j; }
            }
            eqlist[bj] = 0x7fffffff;
            indices[outbase + pos + t] = best;
        }
    }
}

// ---------------------------------------------------------------------------
// Sparse attention, wave-autonomous: 4 waves/block, wave w owns heads {w,w+4}.
// Single barrier (idx load); per-wave LDS chunks; softmax in shuffles.
// ---------------------------------------------------------------------------
__global__ __launch_bounds__(256) void attn_kernel(
    const float* __restrict__ q, const float* __restrict__ k,
    const float* __restrict__ v, const float* __restrict__ og,
    const int* __restrict__ indices, const int* __restrict__ counts,
    float* __restrict__ out) {
    __shared__ int idx[KSEL];
    __shared__ float kw[4][32 * 66];  // per-wave K chunk: 32 rows, stride 66
    __shared__ float qv[4][DH];       // per-wave q vector
    __shared__ float pw[4][KSEL];     // per-wave normalized probs
    int qrow = blockIdx.x;
    int tid = threadIdx.x;
    int lane = tid & 63, w = tid >> 6;
    int cnt = counts[qrow];
    if (tid < KSEL) idx[tid] = (tid < cnt) ? indices[qrow * KSEL + tid] : 0;
    __syncthreads();
    float* kws = kw[w];
    float* qvs = qv[w];
    float* pps = pw[w];
    int j2 = lane & 31, half = lane >> 5;
    int d0 = j2 * 2;
#pragma unroll
    for (int hh = 0; hh < 2; ++hh) {
        int h = w + hh * 4;
        int hb = h * DH;
        qvs[lane] = q[qrow * DD + hb + lane];
        float sc[4];
#pragma unroll
        for (int c = 0; c < 4; ++c) {
            // stage chunk: rows c*32..c*32+31, two rows per iteration
#pragma unroll
            for (int rr = 0; rr < 16; ++rr) {
                int rl = rr * 2 + half;
                int row = idx[c * 32 + rl];
                *(float2*)&kws[rl * 66 + d0] =
                    *(const float2*)(k + (size_t)row * DD + hb + d0);
            }
            // dot: lane handles key j2, d-range [half*32, half*32+32)
            float acc = 0.f;
            const float* kr = kws + j2 * 66 + half * 32;
            const float* qr = qvs + half * 32;
#pragma unroll
            for (int d = 0; d < 32; d += 2) {
                float2 kv = *(const float2*)&kr[d];
                float2 q2 = *(const float2*)&qr[d];
                acc += kv.x * q2.x + kv.y * q2.y;
            }
            acc += __shfl_xor(acc, 32);
            int j = c * 32 + j2;
            sc[c] = (j < cnt) ? acc * 0.125f : -1e30f;
        }
        // softmax (wave-local, halves mirrored)
        float m = fmaxf(fmaxf(sc[0], sc[1]), fmaxf(sc[2], sc[3]));
#pragma unroll
        for (int off = 16; off; off >>= 1) m = fmaxf(m, __shfl_xor(m, off));
        float pc[4], sum = 0.f;
#pragma unroll
        for (int c = 0; c < 4; ++c) {
            pc[c] = __expf(sc[c] - m);
            sum += pc[c];
        }
#pragma unroll
        for (int off = 16; off; off >>= 1) sum += __shfl_xor(sum, off);
        float inv = 1.0f / sum;
        if (half == 0) {
#pragma unroll
            for (int c = 0; c < 4; ++c) pps[c * 32 + j2] = pc[c] * inv;
        }
        // P*V from global, coalesced per key (lane = d)
        float acc2 = 0.f;
#pragma unroll
        for (int c = 0; c < 4; ++c) {
#pragma unroll 16
            for (int jj = 0; jj < 32; ++jj) {
                int j = c * 32 + jj;
                float pj = pps[j];
                int row = idx[j];
                acc2 += pj * v[(size_t)row * DD + hb + lane];
            }
        }
        int o = qrow * DD + hb + lane;
        out[o] = acc2 * og[o];
    }
}

// ---------------------------------------------------------------------------
extern "C" void kernel_launch(void* const* d_in, const int* in_sizes, int n_in,
                              void* d_out, int out_size, void* d_ws, size_t ws_size,
                              hipStream_t stream) {
    const float* x = (const float*)d_in[0];
    const float* Wq = (const float*)d_in[1];
    const float* Wk = (const float*)d_in[2];
    const float* Wv = (const float*)d_in[3];
    const float* Wo = (const float*)d_in[4];
    const float* Wiq = (const float*)d_in[5];
    const float* Wik = (const float*)d_in[6];
    const float* Wiw = (const float*)d_in[7];
    const float* biw = (const float*)d_in[8];
    const float* idx_bias = (const float*)d_in[9];
    const float* Wvg = (const float*)d_in[10];
    const float* bvg = (const float*)d_in[11];
    const float* Wog = (const float*)d_in[12];
    const float* bog = (const float*)d_in[13];
    float* out = (float*)d_out;
    float* ws = (float*)d_ws;

    float* qb = ws;
    float* kb = ws + (1 << 20);
    float* vb = ws + (2 << 20);
    float* vgb = ws + (3 << 20);
    float* ogb = ws + (4 << 20);
    float* qib = ws + (5 << 20);
    float* kib = qib + TT * NI * DI;
    float* wsb = kib + TT * DI;
    float* ab = ws + (6 << 20);
    int* idxb = (int*)(ws + (7 << 20));
    int* cntb = idxb + TT * KSEL;
    unsigned* keysb = (unsigned*)(ws + (8 << 20));

    dim3 blk(256);
    proj_kernel<<<dim3(45, 32), blk, 0, stream>>>(x, Wq, Wk, Wv, Wvg, Wog, Wiq,
                                                  Wik, bvg, bog, qb, kb, vb,
                                                  vgb, ogb, qib, kib);
    iw_kernel<<<TT, blk, 0, stream>>>(x, Wiw, biw, wsb);
    vmul_kernel<<<(TT * DD) / 256, blk, 0, stream>>>(vb, vgb);
    rope_kernel<<<(TT * HEADS * 32) / 256, blk, 0, stream>>>(qb, kb);
    score_kernel<<<528, blk, 0, stream>>>(qib, kib, wsb, idx_bias, keysb);
    topk_kernel<<<TT, blk, 0, stream>>>(keysb, idxb, cntb);
    attn_kernel<<<TT, blk, 0, stream>>>(qb, kb, vb, ogb, idxb, cntb, ab);
    wo_kernel<<<dim3(8, 32), blk, 0, stream>>>(ab, Wo, out);
}

// Round 5
// 315.685 us; speedup vs baseline: 2.6130x; 1.1541x over previous
//
#include <hip/hip_runtime.h>
#include <math.h>

#define TT 2048
#define DD 512
#define HEADS 8
#define DH 64
#define NI 4
#define DI 64
#define KSEL 128

typedef __bf16 bfr;
typedef bfr bf16x8 __attribute__((ext_vector_type(8)));
typedef float f32x4 __attribute__((ext_vector_type(4)));

__device__ __forceinline__ float sigmoidf_(float z) {
    return 1.0f / (1.0f + __expf(-z));
}

__device__ __forceinline__ ushort f2bf(float f) {
    unsigned u = __float_as_uint(f);
    unsigned r = (u + 0x7fffu + ((u >> 16) & 1u)) >> 16;
    return (ushort)r;
}

// ---------------------------------------------------------------------------
// x (fp32) -> bf16
// ---------------------------------------------------------------------------
__global__ void castx_kernel(const float* __restrict__ x, ushort* __restrict__ xb) {
    int i = blockIdx.x * blockDim.x + threadIdx.x;
    xb[i] = f2bf(x[i]);
}

// ---------------------------------------------------------------------------
// Transpose 6 weight matrices [512][512] fp32 -> WT bf16 [mat*512 + n][k]
// ---------------------------------------------------------------------------
__global__ __launch_bounds__(256) void wtrans_kernel(
    const float* __restrict__ W0, const float* __restrict__ W1,
    const float* __restrict__ W2, const float* __restrict__ W3,
    const float* __restrict__ W4, const float* __restrict__ W5,
    ushort* __restrict__ wtb) {
    const float* srcs[6] = {W0, W1, W2, W3, W4, W5};
    const float* W = srcs[blockIdx.z];
    ushort* outp = wtb + (size_t)blockIdx.z * 512 * 512;
    __shared__ float t[32][33];
    int n0 = blockIdx.x * 32, k0 = blockIdx.y * 32;
    int tid = threadIdx.x;
    int c = tid & 31, r8 = tid >> 5;
#pragma unroll
    for (int rr = 0; rr < 32; rr += 8)
        t[r8 + rr][c] = W[(size_t)(k0 + r8 + rr) * 512 + n0 + c];
    __syncthreads();
#pragma unroll
    for (int rr = 0; rr < 32; rr += 8)
        outp[(size_t)(n0 + r8 + rr) * 512 + k0 + c] = f2bf(t[c][r8 + rr]);
}

// ---------------------------------------------------------------------------
// MFMA bf16 GEMM, 128x128 tile, 4 waves, 4x4 16x16x32 tiles per wave.
// mode 0: proj routing over {q,k,v,vg,og} by blockIdx.x>>2 (sigmoid epi on vg/og)
// mode 1: C = cdirect (N=512)
// ---------------------------------------------------------------------------
__global__ __launch_bounds__(256) void mfma_gemm(
    const ushort* __restrict__ A, const ushort* __restrict__ BT,
    float* __restrict__ qo, float* __restrict__ ko, float* __restrict__ vo,
    float* __restrict__ vgo, float* __restrict__ ogo,
    const float* __restrict__ bvg, const float* __restrict__ bog,
    float* __restrict__ cdirect, int mode) {
    __shared__ __align__(16) ushort As[128][32];
    __shared__ __align__(16) ushort Bs[128][32];
    const int K = 512;
    int tid = threadIdx.x;
    int bm0 = blockIdx.y * 128;
    int bx = blockIdx.x;
    int bn_cat = bx * 128;
    int w = tid >> 6, lane = tid & 63;
    int wm = (w >> 1) * 64, wn = (w & 1) * 64;
    int quad = lane >> 4, mr = lane & 15;
    f32x4 acc[4][4];
#pragma unroll
    for (int i = 0; i < 4; ++i)
#pragma unroll
        for (int j = 0; j < 4; ++j)
#pragma unroll
            for (int r = 0; r < 4; ++r) acc[i][j][r] = 0.f;
    int rs = tid >> 2, cs = (tid & 3) * 8;
    int rs2 = (tid + 256) >> 2;
    for (int k0 = 0; k0 < K; k0 += 32) {
        *(float4*)&As[rs][cs] = *(const float4*)(A + (size_t)(bm0 + rs) * K + k0 + cs);
        *(float4*)&Bs[rs][cs] = *(const float4*)(BT + (size_t)(bn_cat + rs) * K + k0 + cs);
        *(float4*)&As[rs2][cs] = *(const float4*)(A + (size_t)(bm0 + rs2) * K + k0 + cs);
        *(float4*)&Bs[rs2][cs] = *(const float4*)(BT + (size_t)(bn_cat + rs2) * K + k0 + cs);
        __syncthreads();
        bf16x8 af[4], bfv[4];
#pragma unroll
        for (int i = 0; i < 4; ++i)
            af[i] = *(const bf16x8*)&As[wm + i * 16 + mr][quad * 8];
#pragma unroll
        for (int j = 0; j < 4; ++j)
            bfv[j] = *(const bf16x8*)&Bs[wn + j * 16 + mr][quad * 8];
#pragma unroll
        for (int i = 0; i < 4; ++i)
#pragma unroll
            for (int j = 0; j < 4; ++j)
                acc[i][j] = __builtin_amdgcn_mfma_f32_16x16x32_bf16(
                    af[i], bfv[j], acc[i][j], 0, 0, 0);
        __syncthreads();
    }
    if (mode == 1) {
#pragma unroll
        for (int i = 0; i < 4; ++i)
#pragma unroll
            for (int j = 0; j < 4; ++j) {
                int col = bn_cat + wn + j * 16 + mr;
#pragma unroll
                for (int r = 0; r < 4; ++r) {
                    int row = bm0 + wm + i * 16 + quad * 4 + r;
                    cdirect[(size_t)row * 512 + col] = acc[i][j][r];
                }
            }
    } else {
        int mat = bx >> 2;
        float* C = mat == 0 ? qo : mat == 1 ? ko : mat == 2 ? vo : mat == 3 ? vgo : ogo;
        const float* bias = mat == 3 ? bvg : mat == 4 ? bog : nullptr;
        int bn0 = (bx & 3) * 128;
#pragma unroll
        for (int i = 0; i < 4; ++i)
#pragma unroll
            for (int j = 0; j < 4; ++j) {
                int col = bn0 + wn + j * 16 + mr;
                float bv = bias ? bias[col] : 0.f;
#pragma unroll
                for (int r = 0; r < 4; ++r) {
                    int row = bm0 + wm + i * 16 + quad * 4 + r;
                    float val = acc[i][j][r];
                    if (bias) val = sigmoidf_(val + bv);
                    C[(size_t)row * 512 + col] = val;
                }
            }
    }
}

// ---------------------------------------------------------------------------
// fp32 64x64 GEMM tile (kept for the exact fp32 score path: Wiq, Wik)
// ---------------------------------------------------------------------------
__device__ __forceinline__ void gemm_tile64(const float* __restrict__ A,
                                            const float* __restrict__ B,
                                            float* __restrict__ C,
                                            int N, int K, int bm, int bn0) {
    __shared__ float Ast[16][64];
    __shared__ float Bs[16][64];
    int tid = threadIdx.x;
    int tx = tid & 15, ty = tid >> 4;
    int ma = tid >> 2, kq = tid & 3;
    int kb_ = tid >> 4, n4 = tid & 15;
    float acc[4][4] = {};
    for (int k0 = 0; k0 < K; k0 += 16) {
        float4 av = *(const float4*)(A + (size_t)(bm + ma) * K + k0 + kq * 4);
        *(float4*)&Bs[kb_][n4 * 4] =
            *(const float4*)(B + (size_t)(k0 + kb_) * N + bn0 + n4 * 4);
        Ast[kq * 4 + 0][ma] = av.x;
        Ast[kq * 4 + 1][ma] = av.y;
        Ast[kq * 4 + 2][ma] = av.z;
        Ast[kq * 4 + 3][ma] = av.w;
        __syncthreads();
#pragma unroll
        for (int kk = 0; kk < 16; ++kk) {
            float4 a4 = *(const float4*)&Ast[kk][ty * 4];
            float4 b4 = *(const float4*)&Bs[kk][tx * 4];
            float af[4] = {a4.x, a4.y, a4.z, a4.w};
            float bf[4] = {b4.x, b4.y, b4.z, b4.w};
#pragma unroll
            for (int i = 0; i < 4; ++i)
#pragma unroll
                for (int j = 0; j < 4; ++j) acc[i][j] += af[i] * bf[j];
        }
        __syncthreads();
    }
#pragma unroll
    for (int i = 0; i < 4; ++i) {
        int mrow = bm + ty * 4 + i;
#pragma unroll
        for (int j = 0; j < 4; ++j)
            C[(size_t)mrow * N + bn0 + tx * 4 + j] = acc[i][j];
    }
}

// Wiq (4 n-blocks) + Wik (1 n-block), fp32 exact
__global__ __launch_bounds__(256) void proj32_kernel(
    const float* __restrict__ x, const float* __restrict__ Wiq,
    const float* __restrict__ Wik, float* __restrict__ qib,
    float* __restrict__ kib) {
    int bn = blockIdx.x, bm = blockIdx.y * 64;
    if (bn < 4)
        gemm_tile64(x, Wiq, qib, 256, 512, bm, bn * 64);
    else
        gemm_tile64(x, Wik, kib, 64, 512, bm, 0);
}

__global__ __launch_bounds__(256) void iw_kernel(const float* __restrict__ x,
                                                 const float* __restrict__ Wiw,
                                                 const float* __restrict__ biw,
                                                 float* __restrict__ wsig) {
    int t = blockIdx.x;
    int tid = threadIdx.x;
    int lane = tid & 63, c = tid >> 6;
    float acc = 0.f;
    for (int k = lane; k < DD; k += 64) acc += x[t * DD + k] * Wiw[k * NI + c];
#pragma unroll
    for (int off = 32; off; off >>= 1) acc += __shfl_down(acc, off);
    if (lane == 0) wsig[t * NI + c] = sigmoidf_(acc + biw[c]);
}

__global__ void vmul_kernel(float* __restrict__ v, const float* __restrict__ vg) {
    int i = blockIdx.x * blockDim.x + threadIdx.x;
    v[i] *= vg[i];
}

__global__ void rope_kernel(float* __restrict__ q, float* __restrict__ k) {
    int i = blockIdx.x * blockDim.x + threadIdx.x;
    int j = i & 31;
    int h = (i >> 5) & 7;
    int t = i >> 8;
    if (t >= TT) return;
    const float L2_10000 = 13.287712379549449f;
    float inv = exp2f(-(float)j * (1.0f / 32.0f) * L2_10000);
    float ang = (float)t * inv;
    float c = cosf(ang), s = sinf(ang);
    int base = t * DD + h * DH;
    float q1 = q[base + j], q2 = q[base + j + 32];
    q[base + j] = q1 * c - q2 * s;
    q[base + j + 32] = q2 * c + q1 * s;
    float k1 = k[base + j], k2 = k[base + j + 32];
    k[base + j] = k1 * c - k2 * s;
    k[base + j + 32] = k2 * c + k1 * s;
}

// ---------------------------------------------------------------------------
// Index-score GEMM over lower-triangle 64x64 tiles -> monotone uint keys.
// ---------------------------------------------------------------------------
__global__ __launch_bounds__(256) void score_kernel(
    const float* __restrict__ qi, const float* __restrict__ ki,
    const float* __restrict__ wsig, const float* __restrict__ idx_bias,
    unsigned* __restrict__ keys) {
    __shared__ float As[64][65];
    __shared__ float Bs[64][65];
    int b = blockIdx.x;
    int bq = (int)((sqrtf(8.0f * (float)b + 1.0f) - 1.0f) * 0.5f);
    while ((bq + 1) * (bq + 2) / 2 <= b) ++bq;
    while (bq * (bq + 1) / 2 > b) --bq;
    int bk = b - bq * (bq + 1) / 2;
    int q0 = bq * 64, k0 = bk * 64;
    int tid = threadIdx.x;
    int tx = tid & 15, ty = tid >> 4;
    float fin[4][4] = {};
#pragma unroll
    for (int h = 0; h < NI; ++h) {
#pragma unroll
        for (int i = 0; i < 4; ++i) {
            int e = tid + i * 256;
            int r = e >> 4, c4 = e & 15;
            float4 av = *(const float4*)(qi + (size_t)(q0 + r) * (NI * DI) + h * DI + c4 * 4);
            As[r][c4 * 4 + 0] = av.x;
            As[r][c4 * 4 + 1] = av.y;
            As[r][c4 * 4 + 2] = av.z;
            As[r][c4 * 4 + 3] = av.w;
            float4 bv = *(const float4*)(ki + (size_t)(k0 + r) * DI + c4 * 4);
            Bs[c4 * 4 + 0][r] = bv.x;
            Bs[c4 * 4 + 1][r] = bv.y;
            Bs[c4 * 4 + 2][r] = bv.z;
            Bs[c4 * 4 + 3][r] = bv.w;
        }
        __syncthreads();
        float raw[4][4] = {};
#pragma unroll 8
        for (int kk = 0; kk < 64; ++kk) {
            float a[4], bb[4];
#pragma unroll
            for (int i = 0; i < 4; ++i) a[i] = As[ty * 4 + i][kk];
#pragma unroll
            for (int j = 0; j < 4; ++j) bb[j] = Bs[kk][tx * 4 + j];
#pragma unroll
            for (int i = 0; i < 4; ++i)
#pragma unroll
                for (int j = 0; j < 4; ++j) raw[i][j] += a[i] * bb[j];
        }
        float bh = idx_bias[h];
        float w4[4];
#pragma unroll
        for (int i = 0; i < 4; ++i) w4[i] = wsig[(q0 + ty * 4 + i) * NI + h];
#pragma unroll
        for (int i = 0; i < 4; ++i)
#pragma unroll
            for (int j = 0; j < 4; ++j)
                fin[i][j] += sigmoidf_(raw[i][j] * 0.125f + bh) * w4[i];
        __syncthreads();
    }
#pragma unroll
    for (int i = 0; i < 4; ++i) {
        int qq = q0 + ty * 4 + i;
#pragma unroll
        for (int j = 0; j < 4; ++j) {
            int kk = k0 + tx * 4 + j;
            unsigned key = 0;
            if (kk <= qq) {
                unsigned u = __float_as_uint(fin[i][j]);
                key = (u & 0x80000000u) ? ~u : (u | 0x80000000u);
            }
            keys[(size_t)qq * TT + kk] = key;
        }
    }
}

// ---------------------------------------------------------------------------
// Exact per-row top-K via MSB-first radix select. Ties -> lowest index.
// ---------------------------------------------------------------------------
__global__ __launch_bounds__(256) void topk_kernel(
    const unsigned* __restrict__ keys, int* __restrict__ indices,
    int* __restrict__ counts) {
    __shared__ unsigned ks_[TT];
    __shared__ unsigned hist[256];
    __shared__ unsigned s_prefix, s_above;
    __shared__ int eqlist[256];
    __shared__ unsigned eqcount, outpos;
    int qrow = blockIdx.x;
    int tid = threadIdx.x;
    int n = qrow + 1;
    if (n <= KSEL) {
        if (tid < n) indices[qrow * KSEL + tid] = tid;
        if (tid == 0) counts[qrow] = n;
        return;
    }
    if (tid == 0) counts[qrow] = KSEL;
    const unsigned* krow = keys + (size_t)qrow * TT;
    for (int k = tid; k < n; k += 256) ks_[k] = krow[k];
    __syncthreads();
    unsigned prefix = 0;
    int remaining = KSEL;
    for (int level = 24; level >= 0; level -= 8) {
        hist[tid] = 0;
        __syncthreads();
        for (int k = tid; k < n; k += 256) {
            unsigned key = ks_[k];
            bool match = ((unsigned long long)key >> (level + 8)) == (unsigned long long)prefix;
            if (match) atomicAdd(&hist[(key >> level) & 255], 1u);
        }
        __syncthreads();
#pragma unroll
        for (int off = 1; off < 256; off <<= 1) {
            unsigned vv = (tid + off < 256) ? hist[tid + off] : 0u;
            __syncthreads();
            hist[tid] += vv;
            __syncthreads();
        }
        if (hist[tid] >= (unsigned)remaining &&
            (tid == 255 || hist[tid + 1] < (unsigned)remaining)) {
            s_prefix = (prefix << 8) | (unsigned)tid;
            s_above = (tid == 255) ? 0u : hist[tid + 1];
        }
        __syncthreads();
        prefix = s_prefix;
        remaining -= (int)s_above;
        __syncthreads();
    }
    if (tid == 0) { eqcount = 0; outpos = 0; }
    __syncthreads();
    int outbase = qrow * KSEL;
    for (int k = tid; k < n; k += 256) {
        unsigned key = ks_[k];
        if (key > prefix) {
            unsigned p = atomicAdd(&outpos, 1u);
            indices[outbase + p] = k;
        } else if (key == prefix) {
            unsigned e = atomicAdd(&eqcount, 1u);
            if (e < 256) eqlist[e] = k;
        }
    }
    __syncthreads();
    if (tid == 0) {
        int r = remaining;
        int E = (int)eqcount;
        if (E > 256) E = 256;
        if (r > E) r = E;
        int pos = (int)outpos;
        for (int t = 0; t < r; ++t) {
            int best = 0x7fffffff, bj = -1;
            for (int j = 0; j < E; ++j) {
                int vv = eqlist[j];
                if (vv < best) { best = vv; bj = j; }
            }
            eqlist[bj] = 0x7fffffff;
            indices[outbase + pos + t] = best;
        }
    }
}

// ---------------------------------------------------------------------------
// Sparse attention, wave-autonomous; output written as bf16 for the Wo MFMA.
// ---------------------------------------------------------------------------
__global__ __launch_bounds__(256) void attn_kernel(
    const float* __restrict__ q, const float* __restrict__ k,
    const float* __restrict__ v, const float* __restrict__ og,
    const int* __restrict__ indices, const int* __restrict__ counts,
    ushort* __restrict__ out) {
    __shared__ int idx[KSEL];
    __shared__ float kw[4][32 * 66];
    __shared__ float qv[4][DH];
    __shared__ float pw[4][KSEL];
    int qrow = blockIdx.x;
    int tid = threadIdx.x;
    int lane = tid & 63, w = tid >> 6;
    int cnt = counts[qrow];
    if (tid < KSEL) idx[tid] = (tid < cnt) ? indices[qrow * KSEL + tid] : 0;
    __syncthreads();
    float* kws = kw[w];
    float* qvs = qv[w];
    float* pps = pw[w];
    int j2 = lane & 31, half = lane >> 5;
    int d0 = j2 * 2;
#pragma unroll
    for (int hh = 0; hh < 2; ++hh) {
        int h = w + hh * 4;
        int hb = h * DH;
        qvs[lane] = q[qrow * DD + hb + lane];
        float sc[4];
#pragma unroll
        for (int c = 0; c < 4; ++c) {
#pragma unroll
            for (int rr = 0; rr < 16; ++rr) {
                int rl = rr * 2 + half;
                int row = idx[c * 32 + rl];
                *(float2*)&kws[rl * 66 + d0] =
                    *(const float2*)(k + (size_t)row * DD + hb + d0);
            }
            float acc = 0.f;
            const float* kr = kws + j2 * 66 + half * 32;
            const float* qr = qvs + half * 32;
#pragma unroll
            for (int d = 0; d < 32; d += 2) {
                float2 kv = *(const float2*)&kr[d];
                float2 q2 = *(const float2*)&qr[d];
                acc += kv.x * q2.x + kv.y * q2.y;
            }
            acc += __shfl_xor(acc, 32);
            int j = c * 32 + j2;
            sc[c] = (j < cnt) ? acc * 0.125f : -1e30f;
        }
        float m = fmaxf(fmaxf(sc[0], sc[1]), fmaxf(sc[2], sc[3]));
#pragma unroll
        for (int off = 16; off; off >>= 1) m = fmaxf(m, __shfl_xor(m, off));
        float pc[4], sum = 0.f;
#pragma unroll
        for (int c = 0; c < 4; ++c) {
            pc[c] = __expf(sc[c] - m);
            sum += pc[c];
        }
#pragma unroll
        for (int off = 16; off; off >>= 1) sum += __shfl_xor(sum, off);
        float inv = 1.0f / sum;
        if (half == 0) {
#pragma unroll
            for (int c = 0; c < 4; ++c) pps[c * 32 + j2] = pc[c] * inv;
        }
        float acc2 = 0.f;
#pragma unroll
        for (int c = 0; c < 4; ++c) {
#pragma unroll 16
            for (int jj = 0; jj < 32; ++jj) {
                int j = c * 32 + jj;
                float pj = pps[j];
                int row = idx[j];
                acc2 += pj * v[(size_t)row * DD + hb + lane];
            }
        }
        int o = qrow * DD + hb + lane;
        out[o] = f2bf(acc2 * og[o]);
    }
}

// ---------------------------------------------------------------------------
extern "C" void kernel_launch(void* const* d_in, const int* in_sizes, int n_in,
                              void* d_out, int out_size, void* d_ws, size_t ws_size,
                              hipStream_t stream) {
    const float* x = (const float*)d_in[0];
    const float* Wq = (const float*)d_in[1];
    const float* Wk = (const float*)d_in[2];
    const float* Wv = (const float*)d_in[3];
    const float* Wo = (const float*)d_in[4];
    const float* Wiq = (const float*)d_in[5];
    const float* Wik = (const float*)d_in[6];
    const float* Wiw = (const float*)d_in[7];
    const float* biw = (const float*)d_in[8];
    const float* idx_bias = (const float*)d_in[9];
    const float* Wvg = (const float*)d_in[10];
    const float* bvg = (const float*)d_in[11];
    const float* Wog = (const float*)d_in[12];
    const float* bog = (const float*)d_in[13];
    float* out = (float*)d_out;
    float* ws = (float*)d_ws;

    float* qb = ws;                              // 1M f
    float* kb = ws + (1 << 20);
    float* vb = ws + (2 << 20);
    float* vgb = ws + (3 << 20);
    float* ogb = ws + (4 << 20);
    float* qib = ws + (5 << 20);                 // 512K
    float* kib = qib + TT * NI * DI;             // 128K
    float* wsb = kib + TT * DI;                  // 8K
    ushort* xb = (ushort*)(ws + (6 << 20));      // 1M ushort = 512K f
    ushort* wtb = (ushort*)(ws + (6 << 20) + (512 << 10));  // 6*512*512 ushort
    int* idxb = (int*)(ws + (7 << 20) + (512 << 10));
    int* cntb = idxb + TT * KSEL;
    unsigned* keysb = (unsigned*)(ws + (8 << 20));          // 4M u (16MB)
    ushort* ab_bf = (ushort*)(ws + (8 << 20));              // overlays dead keysb

    dim3 blk(256);
    castx_kernel<<<TT * DD / 256, blk, 0, stream>>>(x, xb);
    wtrans_kernel<<<dim3(16, 16, 6), blk, 0, stream>>>(Wq, Wk, Wv, Wvg, Wog, Wo, wtb);
    proj32_kernel<<<dim3(5, 32), blk, 0, stream>>>(x, Wiq, Wik, qib, kib);
    iw_kernel<<<TT, blk, 0, stream>>>(x, Wiw, biw, wsb);
    mfma_gemm<<<dim3(20, 16), blk, 0, stream>>>(xb, wtb, qb, kb, vb, vgb, ogb,
                                                bvg, bog, nullptr, 0);
    vmul_kernel<<<(TT * DD) / 256, blk, 0, stream>>>(vb, vgb);
    rope_kernel<<<(TT * HEADS * 32) / 256, blk, 0, stream>>>(qb, kb);
    score_kernel<<<528, blk, 0, stream>>>(qib, kib, wsb, idx_bias, keysb);
    topk_kernel<<<TT, blk, 0, stream>>>(keysb, idxb, cntb);
    attn_kernel<<<TT, blk, 0, stream>>>(qb, kb, vb, ogb, idxb, cntb, ab_bf);
    mfma_gemm<<<dim3(4, 16), blk, 0, stream>>>(ab_bf, wtb + (size_t)5 * 512 * 512,
                                               nullptr, nullptr, nullptr, nullptr,
                                               nullptr, nullptr, nullptr, out, 1);
}

// Round 6
// 282.671 us; speedup vs baseline: 2.9182x; 1.1168x over previous
//
#include <hip/hip_runtime.h>
#include <math.h>

#define TT 2048
#define DD 512
#define HEADS 8
#define DH 64
#define NI 4
#define DI 64
#define KSEL 128

typedef __bf16 bfr;
typedef bfr bf16x8 __attribute__((ext_vector_type(8)));
typedef float f32x4 __attribute__((ext_vector_type(4)));

__device__ __forceinline__ float sigmoidf_(float z) {
    return 1.0f / (1.0f + __expf(-z));
}

__device__ __forceinline__ ushort f2bf(float f) {
    unsigned u = __float_as_uint(f);
    unsigned r = (u + 0x7fffu + ((u >> 16) & 1u)) >> 16;
    return (ushort)r;
}

__device__ __forceinline__ float bf2f(ushort u) {
    return __uint_as_float(((unsigned)u) << 16);
}

// ---------------------------------------------------------------------------
__global__ void castx_kernel(const float* __restrict__ x, ushort* __restrict__ xb) {
    int i = blockIdx.x * blockDim.x + threadIdx.x;
    xb[i] = f2bf(x[i]);
}

// Transpose 6 weight matrices [512][512] fp32 -> WT bf16 [mat*512 + n][k]
__global__ __launch_bounds__(256) void wtrans_kernel(
    const float* __restrict__ W0, const float* __restrict__ W1,
    const float* __restrict__ W2, const float* __restrict__ W3,
    const float* __restrict__ W4, const float* __restrict__ W5,
    ushort* __restrict__ wtb) {
    const float* srcs[6] = {W0, W1, W2, W3, W4, W5};
    const float* W = srcs[blockIdx.z];
    ushort* outp = wtb + (size_t)blockIdx.z * 512 * 512;
    __shared__ float t[32][33];
    int n0 = blockIdx.x * 32, k0 = blockIdx.y * 32;
    int tid = threadIdx.x;
    int c = tid & 31, r8 = tid >> 5;
#pragma unroll
    for (int rr = 0; rr < 32; rr += 8)
        t[r8 + rr][c] = W[(size_t)(k0 + r8 + rr) * 512 + n0 + c];
    __syncthreads();
#pragma unroll
    for (int rr = 0; rr < 32; rr += 8)
        outp[(size_t)(n0 + r8 + rr) * 512 + k0 + c] = f2bf(t[c][r8 + rr]);
}

// ---------------------------------------------------------------------------
// MFMA bf16 GEMM, 128x128 tile, 4 waves, 4x4 16x16x32 tiles per wave.
// ---------------------------------------------------------------------------
__global__ __launch_bounds__(256) void mfma_gemm(
    const ushort* __restrict__ A, const ushort* __restrict__ BT,
    float* __restrict__ qo, float* __restrict__ ko, float* __restrict__ vo,
    float* __restrict__ vgo, float* __restrict__ ogo,
    const float* __restrict__ bvg, const float* __restrict__ bog,
    float* __restrict__ cdirect, int mode) {
    __shared__ __align__(16) ushort As[128][32];
    __shared__ __align__(16) ushort Bs[128][32];
    const int K = 512;
    int tid = threadIdx.x;
    int bm0 = blockIdx.y * 128;
    int bx = blockIdx.x;
    int bn_cat = bx * 128;
    int w = tid >> 6, lane = tid & 63;
    int wm = (w >> 1) * 64, wn = (w & 1) * 64;
    int quad = lane >> 4, mr = lane & 15;
    f32x4 acc[4][4];
#pragma unroll
    for (int i = 0; i < 4; ++i)
#pragma unroll
        for (int j = 0; j < 4; ++j)
#pragma unroll
            for (int r = 0; r < 4; ++r) acc[i][j][r] = 0.f;
    int rs = tid >> 2, cs = (tid & 3) * 8;
    int rs2 = (tid + 256) >> 2;
    for (int k0 = 0; k0 < K; k0 += 32) {
        *(float4*)&As[rs][cs] = *(const float4*)(A + (size_t)(bm0 + rs) * K + k0 + cs);
        *(float4*)&Bs[rs][cs] = *(const float4*)(BT + (size_t)(bn_cat + rs) * K + k0 + cs);
        *(float4*)&As[rs2][cs] = *(const float4*)(A + (size_t)(bm0 + rs2) * K + k0 + cs);
        *(float4*)&Bs[rs2][cs] = *(const float4*)(BT + (size_t)(bn_cat + rs2) * K + k0 + cs);
        __syncthreads();
        bf16x8 af[4], bfv[4];
#pragma unroll
        for (int i = 0; i < 4; ++i)
            af[i] = *(const bf16x8*)&As[wm + i * 16 + mr][quad * 8];
#pragma unroll
        for (int j = 0; j < 4; ++j)
            bfv[j] = *(const bf16x8*)&Bs[wn + j * 16 + mr][quad * 8];
#pragma unroll
        for (int i = 0; i < 4; ++i)
#pragma unroll
            for (int j = 0; j < 4; ++j)
                acc[i][j] = __builtin_amdgcn_mfma_f32_16x16x32_bf16(
                    af[i], bfv[j], acc[i][j], 0, 0, 0);
        __syncthreads();
    }
    if (mode == 1) {
#pragma unroll
        for (int i = 0; i < 4; ++i)
#pragma unroll
            for (int j = 0; j < 4; ++j) {
                int col = bn_cat + wn + j * 16 + mr;
#pragma unroll
                for (int r = 0; r < 4; ++r) {
                    int row = bm0 + wm + i * 16 + quad * 4 + r;
                    cdirect[(size_t)row * 512 + col] = acc[i][j][r];
                }
            }
    } else {
        int mat = bx >> 2;
        float* C = mat == 0 ? qo : mat == 1 ? ko : mat == 2 ? vo : mat == 3 ? vgo : ogo;
        const float* bias = mat == 3 ? bvg : mat == 4 ? bog : nullptr;
        int bn0 = (bx & 3) * 128;
#pragma unroll
        for (int i = 0; i < 4; ++i)
#pragma unroll
            for (int j = 0; j < 4; ++j) {
                int col = bn0 + wn + j * 16 + mr;
                float bv = bias ? bias[col] : 0.f;
#pragma unroll
                for (int r = 0; r < 4; ++r) {
                    int row = bm0 + wm + i * 16 + quad * 4 + r;
                    float val = acc[i][j][r];
                    if (bias) val = sigmoidf_(val + bv);
                    C[(size_t)row * 512 + col] = val;
                }
            }
    }
}

// ---------------------------------------------------------------------------
// fp32 64x64 GEMM tile (exact fp32 score path: Wiq, Wik)
// ---------------------------------------------------------------------------
__device__ __forceinline__ void gemm_tile64(const float* __restrict__ A,
                                            const float* __restrict__ B,
                                            float* __restrict__ C,
                                            int N, int K, int bm, int bn0) {
    __shared__ float Ast[16][64];
    __shared__ float Bs[16][64];
    int tid = threadIdx.x;
    int tx = tid & 15, ty = tid >> 4;
    int ma = tid >> 2, kq = tid & 3;
    int kb_ = tid >> 4, n4 = tid & 15;
    float acc[4][4] = {};
    for (int k0 = 0; k0 < K; k0 += 16) {
        float4 av = *(const float4*)(A + (size_t)(bm + ma) * K + k0 + kq * 4);
        *(float4*)&Bs[kb_][n4 * 4] =
            *(const float4*)(B + (size_t)(k0 + kb_) * N + bn0 + n4 * 4);
        Ast[kq * 4 + 0][ma] = av.x;
        Ast[kq * 4 + 1][ma] = av.y;
        Ast[kq * 4 + 2][ma] = av.z;
        Ast[kq * 4 + 3][ma] = av.w;
        __syncthreads();
#pragma unroll
        for (int kk = 0; kk < 16; ++kk) {
            float4 a4 = *(const float4*)&Ast[kk][ty * 4];
            float4 b4 = *(const float4*)&Bs[kk][tx * 4];
            float af[4] = {a4.x, a4.y, a4.z, a4.w};
            float bf[4] = {b4.x, b4.y, b4.z, b4.w};
#pragma unroll
            for (int i = 0; i < 4; ++i)
#pragma unroll
                for (int j = 0; j < 4; ++j) acc[i][j] += af[i] * bf[j];
        }
        __syncthreads();
    }
#pragma unroll
    for (int i = 0; i < 4; ++i) {
        int mrow = bm + ty * 4 + i;
#pragma unroll
        for (int j = 0; j < 4; ++j)
            C[(size_t)mrow * N + bn0 + tx * 4 + j] = acc[i][j];
    }
}

__global__ __launch_bounds__(256) void proj32_kernel(
    const float* __restrict__ x, const float* __restrict__ Wiq,
    const float* __restrict__ Wik, float* __restrict__ qib,
    float* __restrict__ kib) {
    int bn = blockIdx.x, bm = blockIdx.y * 64;
    if (bn < 4)
        gemm_tile64(x, Wiq, qib, 256, 512, bm, bn * 64);
    else
        gemm_tile64(x, Wik, kib, 64, 512, bm, 0);
}

__global__ __launch_bounds__(256) void iw_kernel(const float* __restrict__ x,
                                                 const float* __restrict__ Wiw,
                                                 const float* __restrict__ biw,
                                                 float* __restrict__ wsig) {
    int t = blockIdx.x;
    int tid = threadIdx.x;
    int lane = tid & 63, c = tid >> 6;
    float acc = 0.f;
    for (int k = lane; k < DD; k += 64) acc += x[t * DD + k] * Wiw[k * NI + c];
#pragma unroll
    for (int off = 32; off; off >>= 1) acc += __shfl_down(acc, off);
    if (lane == 0) wsig[t * NI + c] = sigmoidf_(acc + biw[c]);
}

// v_bf16 = bf16(v * vg)
__global__ void vmul_kernel(const float* __restrict__ v,
                            const float* __restrict__ vg,
                            ushort* __restrict__ v16) {
    int i = blockIdx.x * blockDim.x + threadIdx.x;
    v16[i] = f2bf(v[i] * vg[i]);
}

// RoPE: q updated in place (fp32); k emitted as bf16 only.
__global__ void rope_kernel(float* __restrict__ q, const float* __restrict__ k,
                            ushort* __restrict__ k16) {
    int i = blockIdx.x * blockDim.x + threadIdx.x;
    int j = i & 31;
    int h = (i >> 5) & 7;
    int t = i >> 8;
    if (t >= TT) return;
    const float L2_10000 = 13.287712379549449f;
    float inv = exp2f(-(float)j * (1.0f / 32.0f) * L2_10000);
    float ang = (float)t * inv;
    float c = cosf(ang), s = sinf(ang);
    int base = t * DD + h * DH;
    float q1 = q[base + j], q2 = q[base + j + 32];
    q[base + j] = q1 * c - q2 * s;
    q[base + j + 32] = q2 * c + q1 * s;
    float k1 = k[base + j], k2 = k[base + j + 32];
    k16[base + j] = f2bf(k1 * c - k2 * s);
    k16[base + j + 32] = f2bf(k2 * c + k1 * s);
}

// ---------------------------------------------------------------------------
// Index-score GEMM over lower-triangle 64x64 tiles -> monotone uint keys.
// ---------------------------------------------------------------------------
__global__ __launch_bounds__(256) void score_kernel(
    const float* __restrict__ qi, const float* __restrict__ ki,
    const float* __restrict__ wsig, const float* __restrict__ idx_bias,
    unsigned* __restrict__ keys) {
    __shared__ float As[64][65];
    __shared__ float Bs[64][65];
    int b = blockIdx.x;
    int bq = (int)((sqrtf(8.0f * (float)b + 1.0f) - 1.0f) * 0.5f);
    while ((bq + 1) * (bq + 2) / 2 <= b) ++bq;
    while (bq * (bq + 1) / 2 > b) --bq;
    int bk = b - bq * (bq + 1) / 2;
    int q0 = bq * 64, k0 = bk * 64;
    int tid = threadIdx.x;
    int tx = tid & 15, ty = tid >> 4;
    float fin[4][4] = {};
#pragma unroll
    for (int h = 0; h < NI; ++h) {
#pragma unroll
        for (int i = 0; i < 4; ++i) {
            int e = tid + i * 256;
            int r = e >> 4, c4 = e & 15;
            float4 av = *(const float4*)(qi + (size_t)(q0 + r) * (NI * DI) + h * DI + c4 * 4);
            As[r][c4 * 4 + 0] = av.x;
            As[r][c4 * 4 + 1] = av.y;
            As[r][c4 * 4 + 2] = av.z;
            As[r][c4 * 4 + 3] = av.w;
            float4 bv = *(const float4*)(ki + (size_t)(k0 + r) * DI + c4 * 4);
            Bs[c4 * 4 + 0][r] = bv.x;
            Bs[c4 * 4 + 1][r] = bv.y;
            Bs[c4 * 4 + 2][r] = bv.z;
            Bs[c4 * 4 + 3][r] = bv.w;
        }
        __syncthreads();
        float raw[4][4] = {};
#pragma unroll 8
        for (int kk = 0; kk < 64; ++kk) {
            float a[4], bb[4];
#pragma unroll
            for (int i = 0; i < 4; ++i) a[i] = As[ty * 4 + i][kk];
#pragma unroll
            for (int j = 0; j < 4; ++j) bb[j] = Bs[kk][tx * 4 + j];
#pragma unroll
            for (int i = 0; i < 4; ++i)
#pragma unroll
                for (int j = 0; j < 4; ++j) raw[i][j] += a[i] * bb[j];
        }
        float bh = idx_bias[h];
        float w4[4];
#pragma unroll
        for (int i = 0; i < 4; ++i) w4[i] = wsig[(q0 + ty * 4 + i) * NI + h];
#pragma unroll
        for (int i = 0; i < 4; ++i)
#pragma unroll
            for (int j = 0; j < 4; ++j)
                fin[i][j] += sigmoidf_(raw[i][j] * 0.125f + bh) * w4[i];
        __syncthreads();
    }
#pragma unroll
    for (int i = 0; i < 4; ++i) {
        int qq = q0 + ty * 4 + i;
#pragma unroll
        for (int j = 0; j < 4; ++j) {
            int kk = k0 + tx * 4 + j;
            unsigned key = 0;
            if (kk <= qq) {
                unsigned u = __float_as_uint(fin[i][j]);
                key = (u & 0x80000000u) ? ~u : (u | 0x80000000u);
            }
            keys[(size_t)qq * TT + kk] = key;
        }
    }
}

// ---------------------------------------------------------------------------
// Exact per-row top-K via MSB-first radix select. Ties -> lowest index.
// ---------------------------------------------------------------------------
__global__ __launch_bounds__(256) void topk_kernel(
    const unsigned* __restrict__ keys, int* __restrict__ indices,
    int* __restrict__ counts) {
    __shared__ unsigned ks_[TT];
    __shared__ unsigned hist[256];
    __shared__ unsigned s_prefix, s_above;
    __shared__ int eqlist[256];
    __shared__ unsigned eqcount, outpos;
    int qrow = blockIdx.x;
    int tid = threadIdx.x;
    int n = qrow + 1;
    if (n <= KSEL) {
        if (tid < n) indices[qrow * KSEL + tid] = tid;
        if (tid == 0) counts[qrow] = n;
        return;
    }
    if (tid == 0) counts[qrow] = KSEL;
    const unsigned* krow = keys + (size_t)qrow * TT;
    for (int k = tid; k < n; k += 256) ks_[k] = krow[k];
    __syncthreads();
    unsigned prefix = 0;
    int remaining = KSEL;
    for (int level = 24; level >= 0; level -= 8) {
        hist[tid] = 0;
        __syncthreads();
        for (int k = tid; k < n; k += 256) {
            unsigned key = ks_[k];
            bool match = ((unsigned long long)key >> (level + 8)) == (unsigned long long)prefix;
            if (match) atomicAdd(&hist[(key >> level) & 255], 1u);
        }
        __syncthreads();
#pragma unroll
        for (int off = 1; off < 256; off <<= 1) {
            unsigned vv = (tid + off < 256) ? hist[tid + off] : 0u;
            __syncthreads();
            hist[tid] += vv;
            __syncthreads();
        }
        if (hist[tid] >= (unsigned)remaining &&
            (tid == 255 || hist[tid + 1] < (unsigned)remaining)) {
            s_prefix = (prefix << 8) | (unsigned)tid;
            s_above = (tid == 255) ? 0u : hist[tid + 1];
        }
        __syncthreads();
        prefix = s_prefix;
        remaining -= (int)s_above;
        __syncthreads();
    }
    if (tid == 0) { eqcount = 0; outpos = 0; }
    __syncthreads();
    int outbase = qrow * KSEL;
    for (int k = tid; k < n; k += 256) {
        unsigned key = ks_[k];
        if (key > prefix) {
            unsigned p = atomicAdd(&outpos, 1u);
            indices[outbase + p] = k;
        } else if (key == prefix) {
            unsigned e = atomicAdd(&eqcount, 1u);
            if (e < 256) eqlist[e] = k;
        }
    }
    __syncthreads();
    if (tid == 0) {
        int r = remaining;
        int E = (int)eqcount;
        if (E > 256) E = 256;
        if (r > E) r = E;
        int pos = (int)outpos;
        for (int t = 0; t < r; ++t) {
            int best = 0x7fffffff, bj = -1;
            for (int j = 0; j < E; ++j) {
                int vv = eqlist[j];
                if (vv < best) { best = vv; bj = j; }
            }
            eqlist[bj] = 0x7fffffff;
            indices[outbase + pos + t] = best;
        }
    }
}

// ---------------------------------------------------------------------------
// Sparse attention on bf16 K/V, wave-autonomous (wave w owns heads {w,w+4}).
// ---------------------------------------------------------------------------
__global__ __launch_bounds__(256) void attn_kernel(
    const float* __restrict__ q, const ushort* __restrict__ k16,
    const ushort* __restrict__ v16, const float* __restrict__ og,
    const int* __restrict__ indices, const int* __restrict__ counts,
    ushort* __restrict__ out) {
    __shared__ int idx[KSEL];
    __shared__ ushort kw[4][32 * 68];  // per-wave bf16 K chunk, stride 68
    __shared__ float qv[4][DH];
    __shared__ float pw[4][KSEL];
    int qrow = blockIdx.x;
    int tid = threadIdx.x;
    int lane = tid & 63, w = tid >> 6;
    int cnt = counts[qrow];
    if (tid < KSEL) idx[tid] = (tid < cnt) ? indices[qrow * KSEL + tid] : 0;
    __syncthreads();
    ushort* kws = kw[w];
    float* qvs = qv[w];
    float* pps = pw[w];
    int j2 = lane & 31, half = lane >> 5;
    int r4 = lane >> 4;           // 0..3: row-in-group for staging
    int cs = (lane & 15) * 4;     // ushort column for staging
#pragma unroll
    for (int hh = 0; hh < 2; ++hh) {
        int h = w + hh * 4;
        int hb = h * DH;
        qvs[lane] = q[qrow * DD + hb + lane];
        float sc[4];
#pragma unroll
        for (int c = 0; c < 4; ++c) {
            // stage 32 rows x 64 ushorts: 8 iters x 4 rows x (16 lanes x ushort4)
#pragma unroll
            for (int it = 0; it < 8; ++it) {
                int r = it * 4 + r4;
                int row = idx[c * 32 + r];
                *(ushort4*)&kws[r * 68 + cs] =
                    *(const ushort4*)(k16 + (size_t)row * DD + hb + cs);
            }
            // dot: lane handles key j2, d-range [half*32, half*32+32)
            float acc = 0.f;
            const ushort* kr = kws + j2 * 68 + half * 32;
            const float* qr = qvs + half * 32;
#pragma unroll
            for (int dd = 0; dd < 8; ++dd) {
                ushort4 kv = *(const ushort4*)&kr[dd * 4];
                acc += bf2f(kv.x) * qr[dd * 4 + 0] + bf2f(kv.y) * qr[dd * 4 + 1] +
                       bf2f(kv.z) * qr[dd * 4 + 2] + bf2f(kv.w) * qr[dd * 4 + 3];
            }
            acc += __shfl_xor(acc, 32);
            int j = c * 32 + j2;
            sc[c] = (j < cnt) ? acc * 0.125f : -1e30f;
        }
        float m = fmaxf(fmaxf(sc[0], sc[1]), fmaxf(sc[2], sc[3]));
#pragma unroll
        for (int off = 16; off; off >>= 1) m = fmaxf(m, __shfl_xor(m, off));
        float pc[4], sum = 0.f;
#pragma unroll
        for (int c = 0; c < 4; ++c) {
            pc[c] = __expf(sc[c] - m);
            sum += pc[c];
        }
#pragma unroll
        for (int off = 16; off; off >>= 1) sum += __shfl_xor(sum, off);
        float inv = 1.0f / sum;
        if (half == 0) {
#pragma unroll
            for (int c = 0; c < 4; ++c) pps[c * 32 + j2] = pc[c] * inv;
        }
        float acc2 = 0.f;
#pragma unroll
        for (int c = 0; c < 4; ++c) {
#pragma unroll 16
            for (int jj = 0; jj < 32; ++jj) {
                int j = c * 32 + jj;
                float pj = pps[j];
                int row = idx[j];
                acc2 += pj * bf2f(v16[(size_t)row * DD + hb + lane]);
            }
        }
        int o = qrow * DD + hb + lane;
        out[o] = f2bf(acc2 * og[o]);
    }
}

// ---------------------------------------------------------------------------
extern "C" void kernel_launch(void* const* d_in, const int* in_sizes, int n_in,
                              void* d_out, int out_size, void* d_ws, size_t ws_size,
                              hipStream_t stream) {
    const float* x = (const float*)d_in[0];
    const float* Wq = (const float*)d_in[1];
    const float* Wk = (const float*)d_in[2];
    const float* Wv = (const float*)d_in[3];
    const float* Wo = (const float*)d_in[4];
    const float* Wiq = (const float*)d_in[5];
    const float* Wik = (const float*)d_in[6];
    const float* Wiw = (const float*)d_in[7];
    const float* biw = (const float*)d_in[8];
    const float* idx_bias = (const float*)d_in[9];
    const float* Wvg = (const float*)d_in[10];
    const float* bvg = (const float*)d_in[11];
    const float* Wog = (const float*)d_in[12];
    const float* bog = (const float*)d_in[13];
    float* out = (float*)d_out;
    char* base = (char*)d_ws;

    // byte layout (48 MB total)
    float* qb = (float*)(base + 0);                  //  0-4M fp32 q
    float* kb = (float*)(base + (4ull << 20));       //  4-8M fp32 k (pre-rope)
    float* vb = (float*)(base + (8ull << 20));       //  8-12M fp32 v
    float* vgb = (float*)(base + (12ull << 20));     // 12-16M vg (dead after vmul)
    float* ogb = (float*)(base + (16ull << 20));     // 16-20M og gate
    float* qib = (float*)(base + (20ull << 20));     // 20-22M
    float* kib = (float*)(base + (22ull << 20));     // 22-22.5M
    float* wsb = (float*)(base + (22ull << 20) + (512u << 10));  // 32KB
    ushort* xb = (ushort*)(base + (23ull << 20));    // 23-25M bf16 x
    ushort* wtb = (ushort*)(base + (25ull << 20));   // 25-28M bf16 W^T x6
    ushort* kb16 = (ushort*)(base + (28ull << 20));  // 28-30M bf16 K (post-rope)
    ushort* vb16 = (ushort*)(base + (30ull << 20));  // 30-32M bf16 V (gated)
    unsigned* keysb = (unsigned*)(base + (32ull << 20));  // 32-48M (dead after topk)
    ushort* ab_bf = (ushort*)(base + (32ull << 20));      // overlays keysb
    int* idxb = (int*)(base + (12ull << 20));        // overlays dead vgb
    int* cntb = (int*)(base + (13ull << 20) + (512u << 10));

    dim3 blk(256);
    castx_kernel<<<TT * DD / 256, blk, 0, stream>>>(x, xb);
    wtrans_kernel<<<dim3(16, 16, 6), blk, 0, stream>>>(Wq, Wk, Wv, Wvg, Wog, Wo, wtb);
    proj32_kernel<<<dim3(5, 32), blk, 0, stream>>>(x, Wiq, Wik, qib, kib);
    iw_kernel<<<TT, blk, 0, stream>>>(x, Wiw, biw, wsb);
    mfma_gemm<<<dim3(20, 16), blk, 0, stream>>>(xb, wtb, qb, kb, vb, vgb, ogb,
                                                bvg, bog, nullptr, 0);
    vmul_kernel<<<(TT * DD) / 256, blk, 0, stream>>>(vb, vgb, vb16);
    rope_kernel<<<(TT * HEADS * 32) / 256, blk, 0, stream>>>(qb, kb, kb16);
    score_kernel<<<528, blk, 0, stream>>>(qib, kib, wsb, idx_bias, keysb);
    topk_kernel<<<TT, blk, 0, stream>>>(keysb, idxb, cntb);
    attn_kernel<<<TT, blk, 0, stream>>>(qb, kb16, vb16, ogb, idxb, cntb, ab_bf);
    mfma_gemm<<<dim3(4, 16), blk, 0, stream>>>(ab_bf, wtb + (size_t)5 * 512 * 512,
                                               nullptr, nullptr, nullptr, nullptr,
                                               nullptr, nullptr, nullptr, out, 1);
}

// Round 7
// 268.005 us; speedup vs baseline: 3.0779x; 1.0547x over previous
//
#include <hip/hip_runtime.h>
#include <math.h>

#define TT 2048
#define DD 512
#define HEADS 8
#define DH 64
#define NI 4
#define DI 64
#define KSEL 128

typedef __bf16 bfr;
typedef bfr bf16x8 __attribute__((ext_vector_type(8)));
typedef float f32x4 __attribute__((ext_vector_type(4)));

__device__ __forceinline__ float sigmoidf_(float z) {
    return 1.0f / (1.0f + __expf(-z));
}

__device__ __forceinline__ ushort f2bf(float f) {
    unsigned u = __float_as_uint(f);
    unsigned r = (u + 0x7fffu + ((u >> 16) & 1u)) >> 16;
    return (ushort)r;
}

__device__ __forceinline__ float bf2f(ushort u) {
    return __uint_as_float(((unsigned)u) << 16);
}

// ---------------------------------------------------------------------------
__global__ void castx_kernel(const float* __restrict__ x, ushort* __restrict__ xb) {
    int i = blockIdx.x * blockDim.x + threadIdx.x;
    xb[i] = f2bf(x[i]);
}

// Transpose 6 weight matrices [512][512] fp32 -> WT bf16 [mat*512 + n][k]
__global__ __launch_bounds__(256) void wtrans_kernel(
    const float* __restrict__ W0, const float* __restrict__ W1,
    const float* __restrict__ W2, const float* __restrict__ W3,
    const float* __restrict__ W4, const float* __restrict__ W5,
    ushort* __restrict__ wtb) {
    const float* srcs[6] = {W0, W1, W2, W3, W4, W5};
    const float* W = srcs[blockIdx.z];
    ushort* outp = wtb + (size_t)blockIdx.z * 512 * 512;
    __shared__ float t[32][33];
    int n0 = blockIdx.x * 32, k0 = blockIdx.y * 32;
    int tid = threadIdx.x;
    int c = tid & 31, r8 = tid >> 5;
#pragma unroll
    for (int rr = 0; rr < 32; rr += 8)
        t[r8 + rr][c] = W[(size_t)(k0 + r8 + rr) * 512 + n0 + c];
    __syncthreads();
#pragma unroll
    for (int rr = 0; rr < 32; rr += 8)
        outp[(size_t)(n0 + r8 + rr) * 512 + k0 + c] = f2bf(t[c][r8 + rr]);
}

// ---------------------------------------------------------------------------
// MFMA bf16 GEMM, 128x128 tile, 4 waves, 4x4 16x16x32 tiles per wave.
// ---------------------------------------------------------------------------
__global__ __launch_bounds__(256) void mfma_gemm(
    const ushort* __restrict__ A, const ushort* __restrict__ BT,
    float* __restrict__ qo, float* __restrict__ ko, float* __restrict__ vo,
    float* __restrict__ vgo, float* __restrict__ ogo,
    const float* __restrict__ bvg, const float* __restrict__ bog,
    float* __restrict__ cdirect, int mode) {
    __shared__ __align__(16) ushort As[128][32];
    __shared__ __align__(16) ushort Bs[128][32];
    const int K = 512;
    int tid = threadIdx.x;
    int bm0 = blockIdx.y * 128;
    int bx = blockIdx.x;
    int bn_cat = bx * 128;
    int w = tid >> 6, lane = tid & 63;
    int wm = (w >> 1) * 64, wn = (w & 1) * 64;
    int quad = lane >> 4, mr = lane & 15;
    f32x4 acc[4][4];
#pragma unroll
    for (int i = 0; i < 4; ++i)
#pragma unroll
        for (int j = 0; j < 4; ++j)
#pragma unroll
            for (int r = 0; r < 4; ++r) acc[i][j][r] = 0.f;
    int rs = tid >> 2, cs = (tid & 3) * 8;
    int rs2 = (tid + 256) >> 2;
    for (int k0 = 0; k0 < K; k0 += 32) {
        *(float4*)&As[rs][cs] = *(const float4*)(A + (size_t)(bm0 + rs) * K + k0 + cs);
        *(float4*)&Bs[rs][cs] = *(const float4*)(BT + (size_t)(bn_cat + rs) * K + k0 + cs);
        *(float4*)&As[rs2][cs] = *(const float4*)(A + (size_t)(bm0 + rs2) * K + k0 + cs);
        *(float4*)&Bs[rs2][cs] = *(const float4*)(BT + (size_t)(bn_cat + rs2) * K + k0 + cs);
        __syncthreads();
        bf16x8 af[4], bfv[4];
#pragma unroll
        for (int i = 0; i < 4; ++i)
            af[i] = *(const bf16x8*)&As[wm + i * 16 + mr][quad * 8];
#pragma unroll
        for (int j = 0; j < 4; ++j)
            bfv[j] = *(const bf16x8*)&Bs[wn + j * 16 + mr][quad * 8];
#pragma unroll
        for (int i = 0; i < 4; ++i)
#pragma unroll
            for (int j = 0; j < 4; ++j)
                acc[i][j] = __builtin_amdgcn_mfma_f32_16x16x32_bf16(
                    af[i], bfv[j], acc[i][j], 0, 0, 0);
        __syncthreads();
    }
    if (mode == 1) {
#pragma unroll
        for (int i = 0; i < 4; ++i)
#pragma unroll
            for (int j = 0; j < 4; ++j) {
                int col = bn_cat + wn + j * 16 + mr;
#pragma unroll
                for (int r = 0; r < 4; ++r) {
                    int row = bm0 + wm + i * 16 + quad * 4 + r;
                    cdirect[(size_t)row * 512 + col] = acc[i][j][r];
                }
            }
    } else {
        int mat = bx >> 2;
        float* C = mat == 0 ? qo : mat == 1 ? ko : mat == 2 ? vo : mat == 3 ? vgo : ogo;
        const float* bias = mat == 3 ? bvg : mat == 4 ? bog : nullptr;
        int bn0 = (bx & 3) * 128;
#pragma unroll
        for (int i = 0; i < 4; ++i)
#pragma unroll
            for (int j = 0; j < 4; ++j) {
                int col = bn0 + wn + j * 16 + mr;
                float bv = bias ? bias[col] : 0.f;
#pragma unroll
                for (int r = 0; r < 4; ++r) {
                    int row = bm0 + wm + i * 16 + quad * 4 + r;
                    float val = acc[i][j][r];
                    if (bias) val = sigmoidf_(val + bv);
                    C[(size_t)row * 512 + col] = val;
                }
            }
    }
}

// ---------------------------------------------------------------------------
// fp32 64x64 GEMM tile (exact fp32 score path: Wiq, Wik)
// ---------------------------------------------------------------------------
__device__ __forceinline__ void gemm_tile64(const float* __restrict__ A,
                                            const float* __restrict__ B,
                                            float* __restrict__ C,
                                            int N, int K, int bm, int bn0) {
    __shared__ float Ast[16][64];
    __shared__ float Bs[16][64];
    int tid = threadIdx.x;
    int tx = tid & 15, ty = tid >> 4;
    int ma = tid >> 2, kq = tid & 3;
    int kb_ = tid >> 4, n4 = tid & 15;
    float acc[4][4] = {};
    for (int k0 = 0; k0 < K; k0 += 16) {
        float4 av = *(const float4*)(A + (size_t)(bm + ma) * K + k0 + kq * 4);
        *(float4*)&Bs[kb_][n4 * 4] =
            *(const float4*)(B + (size_t)(k0 + kb_) * N + bn0 + n4 * 4);
        Ast[kq * 4 + 0][ma] = av.x;
        Ast[kq * 4 + 1][ma] = av.y;
        Ast[kq * 4 + 2][ma] = av.z;
        Ast[kq * 4 + 3][ma] = av.w;
        __syncthreads();
#pragma unroll
        for (int kk = 0; kk < 16; ++kk) {
            float4 a4 = *(const float4*)&Ast[kk][ty * 4];
            float4 b4 = *(const float4*)&Bs[kk][tx * 4];
            float af[4] = {a4.x, a4.y, a4.z, a4.w};
            float bf[4] = {b4.x, b4.y, b4.z, b4.w};
#pragma unroll
            for (int i = 0; i < 4; ++i)
#pragma unroll
                for (int j = 0; j < 4; ++j) acc[i][j] += af[i] * bf[j];
        }
        __syncthreads();
    }
#pragma unroll
    for (int i = 0; i < 4; ++i) {
        int mrow = bm + ty * 4 + i;
#pragma unroll
        for (int j = 0; j < 4; ++j)
            C[(size_t)mrow * N + bn0 + tx * 4 + j] = acc[i][j];
    }
}

__global__ __launch_bounds__(256) void proj32_kernel(
    const float* __restrict__ x, const float* __restrict__ Wiq,
    const float* __restrict__ Wik, float* __restrict__ qib,
    float* __restrict__ kib) {
    int bn = blockIdx.x, bm = blockIdx.y * 64;
    if (bn < 4)
        gemm_tile64(x, Wiq, qib, 256, 512, bm, bn * 64);
    else
        gemm_tile64(x, Wik, kib, 64, 512, bm, 0);
}

__global__ __launch_bounds__(256) void iw_kernel(const float* __restrict__ x,
                                                 const float* __restrict__ Wiw,
                                                 const float* __restrict__ biw,
                                                 float* __restrict__ wsig) {
    int t = blockIdx.x;
    int tid = threadIdx.x;
    int lane = tid & 63, c = tid >> 6;
    float acc = 0.f;
    for (int k = lane; k < DD; k += 64) acc += x[t * DD + k] * Wiw[k * NI + c];
#pragma unroll
    for (int off = 32; off; off >>= 1) acc += __shfl_down(acc, off);
    if (lane == 0) wsig[t * NI + c] = sigmoidf_(acc + biw[c]);
}

// v_bf16 = bf16(v * vg)
__global__ void vmul_kernel(const float* __restrict__ v,
                            const float* __restrict__ vg,
                            ushort* __restrict__ v16) {
    int i = blockIdx.x * blockDim.x + threadIdx.x;
    v16[i] = f2bf(v[i] * vg[i]);
}

// RoPE: q updated in place (fp32); k emitted as bf16 only.
__global__ void rope_kernel(float* __restrict__ q, const float* __restrict__ k,
                            ushort* __restrict__ k16) {
    int i = blockIdx.x * blockDim.x + threadIdx.x;
    int j = i & 31;
    int h = (i >> 5) & 7;
    int t = i >> 8;
    if (t >= TT) return;
    const float L2_10000 = 13.287712379549449f;
    float inv = exp2f(-(float)j * (1.0f / 32.0f) * L2_10000);
    float ang = (float)t * inv;
    float c = cosf(ang), s = sinf(ang);
    int base = t * DD + h * DH;
    float q1 = q[base + j], q2 = q[base + j + 32];
    q[base + j] = q1 * c - q2 * s;
    q[base + j + 32] = q2 * c + q1 * s;
    float k1 = k[base + j], k2 = k[base + j + 32];
    k16[base + j] = f2bf(k1 * c - k2 * s);
    k16[base + j + 32] = f2bf(k2 * c + k1 * s);
}

// ---------------------------------------------------------------------------
// Index-score GEMM over lower-triangle 64x64 tiles -> monotone uint keys.
// ---------------------------------------------------------------------------
__global__ __launch_bounds__(256) void score_kernel(
    const float* __restrict__ qi, const float* __restrict__ ki,
    const float* __restrict__ wsig, const float* __restrict__ idx_bias,
    unsigned* __restrict__ keys) {
    __shared__ float As[64][65];
    __shared__ float Bs[64][65];
    int b = blockIdx.x;
    int bq = (int)((sqrtf(8.0f * (float)b + 1.0f) - 1.0f) * 0.5f);
    while ((bq + 1) * (bq + 2) / 2 <= b) ++bq;
    while (bq * (bq + 1) / 2 > b) --bq;
    int bk = b - bq * (bq + 1) / 2;
    int q0 = bq * 64, k0 = bk * 64;
    int tid = threadIdx.x;
    int tx = tid & 15, ty = tid >> 4;
    float fin[4][4] = {};
#pragma unroll
    for (int h = 0; h < NI; ++h) {
#pragma unroll
        for (int i = 0; i < 4; ++i) {
            int e = tid + i * 256;
            int r = e >> 4, c4 = e & 15;
            float4 av = *(const float4*)(qi + (size_t)(q0 + r) * (NI * DI) + h * DI + c4 * 4);
            As[r][c4 * 4 + 0] = av.x;
            As[r][c4 * 4 + 1] = av.y;
            As[r][c4 * 4 + 2] = av.z;
            As[r][c4 * 4 + 3] = av.w;
            float4 bv = *(const float4*)(ki + (size_t)(k0 + r) * DI + c4 * 4);
            Bs[c4 * 4 + 0][r] = bv.x;
            Bs[c4 * 4 + 1][r] = bv.y;
            Bs[c4 * 4 + 2][r] = bv.z;
            Bs[c4 * 4 + 3][r] = bv.w;
        }
        __syncthreads();
        float raw[4][4] = {};
#pragma unroll 8
        for (int kk = 0; kk < 64; ++kk) {
            float a[4], bb[4];
#pragma unroll
            for (int i = 0; i < 4; ++i) a[i] = As[ty * 4 + i][kk];
#pragma unroll
            for (int j = 0; j < 4; ++j) bb[j] = Bs[kk][tx * 4 + j];
#pragma unroll
            for (int i = 0; i < 4; ++i)
#pragma unroll
                for (int j = 0; j < 4; ++j) raw[i][j] += a[i] * bb[j];
        }
        float bh = idx_bias[h];
        float w4[4];
#pragma unroll
        for (int i = 0; i < 4; ++i) w4[i] = wsig[(q0 + ty * 4 + i) * NI + h];
#pragma unroll
        for (int i = 0; i < 4; ++i)
#pragma unroll
            for (int j = 0; j < 4; ++j)
                fin[i][j] += sigmoidf_(raw[i][j] * 0.125f + bh) * w4[i];
        __syncthreads();
    }
#pragma unroll
    for (int i = 0; i < 4; ++i) {
        int qq = q0 + ty * 4 + i;
#pragma unroll
        for (int j = 0; j < 4; ++j) {
            int kk = k0 + tx * 4 + j;
            unsigned key = 0;
            if (kk <= qq) {
                unsigned u = __float_as_uint(fin[i][j]);
                key = (u & 0x80000000u) ? ~u : (u | 0x80000000u);
            }
            keys[(size_t)qq * TT + kk] = key;
        }
    }
}

// ---------------------------------------------------------------------------
// Exact per-row top-K via MSB-first radix select. Ties -> lowest index.
// Suffix scan done with wave shuffles (3 barriers/level instead of 17).
// ---------------------------------------------------------------------------
__global__ __launch_bounds__(256) void topk_kernel(
    const unsigned* __restrict__ keys, int* __restrict__ indices,
    int* __restrict__ counts) {
    __shared__ unsigned ks_[TT];
    __shared__ unsigned hist[256];
    __shared__ unsigned wtot[4];
    __shared__ unsigned s_prefix, s_above;
    __shared__ int eqlist[256];
    __shared__ unsigned eqcount, outpos;
    int qrow = blockIdx.x;
    int tid = threadIdx.x;
    int lane = tid & 63, wv = tid >> 6;
    int n = qrow + 1;
    if (n <= KSEL) {
        if (tid < n) indices[qrow * KSEL + tid] = tid;
        if (tid == 0) counts[qrow] = n;
        return;
    }
    if (tid == 0) counts[qrow] = KSEL;
    const unsigned* krow = keys + (size_t)qrow * TT;
    for (int k = tid; k < n; k += 256) ks_[k] = krow[k];
    __syncthreads();
    unsigned prefix = 0;
    int remaining = KSEL;
    for (int level = 24; level >= 0; level -= 8) {
        hist[tid] = 0;
        __syncthreads();
        for (int k = tid; k < n; k += 256) {
            unsigned key = ks_[k];
            bool match = ((unsigned long long)key >> (level + 8)) == (unsigned long long)prefix;
            if (match) atomicAdd(&hist[(key >> level) & 255], 1u);
        }
        __syncthreads();
        // suffix sum via wave shuffles: v = sum(hist[tid..end-of-wave])
        unsigned v = hist[tid];
#pragma unroll
        for (int off = 1; off < 64; off <<= 1) {
            unsigned t = __shfl_down(v, off);
            if (lane + off < 64) v += t;
        }
        if (lane == 0) wtot[wv] = v;
        __syncthreads();
        unsigned add = 0;
#pragma unroll
        for (int u = 1; u < 4; ++u)
            if (wv + u < 4) add += wtot[wv + u];
        v += add;
        hist[tid] = v;
        __syncthreads();
        if (hist[tid] >= (unsigned)remaining &&
            (tid == 255 || hist[tid + 1] < (unsigned)remaining)) {
            s_prefix = (prefix << 8) | (unsigned)tid;
            s_above = (tid == 255) ? 0u : hist[tid + 1];
        }
        __syncthreads();
        prefix = s_prefix;
        remaining -= (int)s_above;
        __syncthreads();
    }
    if (tid == 0) { eqcount = 0; outpos = 0; }
    __syncthreads();
    int outbase = qrow * KSEL;
    for (int k = tid; k < n; k += 256) {
        unsigned key = ks_[k];
        if (key > prefix) {
            unsigned p = atomicAdd(&outpos, 1u);
            indices[outbase + p] = k;
        } else if (key == prefix) {
            unsigned e = atomicAdd(&eqcount, 1u);
            if (e < 256) eqlist[e] = k;
        }
    }
    __syncthreads();
    if (tid == 0) {
        int r = remaining;
        int E = (int)eqcount;
        if (E > 256) E = 256;
        if (r > E) r = E;
        int pos = (int)outpos;
        for (int t = 0; t < r; ++t) {
            int best = 0x7fffffff, bj = -1;
            for (int j = 0; j < E; ++j) {
                int vv = eqlist[j];
                if (vv < best) { best = vv; bj = j; }
            }
            eqlist[bj] = 0x7fffffff;
            indices[outbase + pos + t] = best;
        }
    }
}

// ---------------------------------------------------------------------------
// Sparse attention on bf16 K/V, wave-autonomous (wave w owns heads {w,w+4}).
// PV: lane owns a d-pair; halves split keys; 4 independent accumulators.
// ---------------------------------------------------------------------------
__global__ __launch_bounds__(256) void attn_kernel(
    const float* __restrict__ q, const ushort* __restrict__ k16,
    const ushort* __restrict__ v16, const float* __restrict__ og,
    const int* __restrict__ indices, const int* __restrict__ counts,
    ushort* __restrict__ out) {
    __shared__ int idx[KSEL];
    __shared__ ushort kw[4][32 * 68];  // per-wave bf16 K chunk, stride 68
    __shared__ float qv[4][DH];
    __shared__ float pw[4][KSEL];
    int qrow = blockIdx.x;
    int tid = threadIdx.x;
    int lane = tid & 63, w = tid >> 6;
    int cnt = counts[qrow];
    if (tid < KSEL) idx[tid] = (tid < cnt) ? indices[qrow * KSEL + tid] : 0;
    __syncthreads();
    ushort* kws = kw[w];
    float* qvs = qv[w];
    float* pps = pw[w];
    int j2 = lane & 31, half = lane >> 5;
    int r4 = lane >> 4;           // 0..3: row-in-group for staging
    int cs = (lane & 15) * 4;     // ushort column for staging
    int dp = lane & 31;           // d-pair for PV
#pragma unroll
    for (int hh = 0; hh < 2; ++hh) {
        int h = w + hh * 4;
        int hb = h * DH;
        qvs[lane] = q[qrow * DD + hb + lane];
        float sc[4];
#pragma unroll
        for (int c = 0; c < 4; ++c) {
            // stage 32 rows x 64 ushorts: 8 iters x 4 rows x (16 lanes x ushort4)
#pragma unroll
            for (int it = 0; it < 8; ++it) {
                int r = it * 4 + r4;
                int row = idx[c * 32 + r];
                *(ushort4*)&kws[r * 68 + cs] =
                    *(const ushort4*)(k16 + (size_t)row * DD + hb + cs);
            }
            // dot: lane handles key j2, d-range [half*32, half*32+32)
            float acc0 = 0.f, acc1 = 0.f;
            const ushort* kr = kws + j2 * 68 + half * 32;
            const float* qr = qvs + half * 32;
#pragma unroll
            for (int dd = 0; dd < 8; dd += 2) {
                ushort4 ka = *(const ushort4*)&kr[dd * 4];
                ushort4 kb_ = *(const ushort4*)&kr[dd * 4 + 4];
                acc0 += bf2f(ka.x) * qr[dd * 4 + 0] + bf2f(ka.y) * qr[dd * 4 + 1] +
                        bf2f(ka.z) * qr[dd * 4 + 2] + bf2f(ka.w) * qr[dd * 4 + 3];
                acc1 += bf2f(kb_.x) * qr[dd * 4 + 4] + bf2f(kb_.y) * qr[dd * 4 + 5] +
                        bf2f(kb_.z) * qr[dd * 4 + 6] + bf2f(kb_.w) * qr[dd * 4 + 7];
            }
            float acc = acc0 + acc1;
            acc += __shfl_xor(acc, 32);
            int j = c * 32 + j2;
            sc[c] = (j < cnt) ? acc * 0.125f : -1e30f;
        }
        float m = fmaxf(fmaxf(sc[0], sc[1]), fmaxf(sc[2], sc[3]));
#pragma unroll
        for (int off = 16; off; off >>= 1) m = fmaxf(m, __shfl_xor(m, off));
        float pc[4], sum = 0.f;
#pragma unroll
        for (int c = 0; c < 4; ++c) {
            pc[c] = __expf(sc[c] - m);
            sum += pc[c];
        }
#pragma unroll
        for (int off = 16; off; off >>= 1) sum += __shfl_xor(sum, off);
        float inv = 1.0f / sum;
        if (half == 0) {
#pragma unroll
            for (int c = 0; c < 4; ++c) pps[c * 32 + j2] = pc[c] * inv;
        }
        // PV: lane covers d = dp*2+{0,1}; halves split keys j = 2t+half
        float2 a0 = {0.f, 0.f}, a1 = {0.f, 0.f};
#pragma unroll 8
        for (int t = 0; t < 64; t += 2) {
            int jA = 2 * t + half;
            int jB = 2 * (t + 1) + half;
            int rowA = idx[jA];
            int rowB = idx[jB];
            float pA = pps[jA], pB = pps[jB];
            ushort2 va = *(const ushort2*)(v16 + (size_t)rowA * DD + hb + dp * 2);
            ushort2 vb = *(const ushort2*)(v16 + (size_t)rowB * DD + hb + dp * 2);
            a0.x += pA * bf2f(va.x);
            a0.y += pA * bf2f(va.y);
            a1.x += pB * bf2f(vb.x);
            a1.y += pB * bf2f(vb.y);
        }
        float ax = a0.x + a1.x, ay = a0.y + a1.y;
        ax += __shfl_xor(ax, 32);
        ay += __shfl_xor(ay, 32);
        if (half == 0) {
            int o = qrow * DD + hb + dp * 2;
            float2 g = *(const float2*)(og + o);
            ushort2 r;
            r.x = f2bf(ax * g.x);
            r.y = f2bf(ay * g.y);
            *(ushort2*)(out + o) = r;
        }
    }
}

// ---------------------------------------------------------------------------
extern "C" void kernel_launch(void* const* d_in, const int* in_sizes, int n_in,
                              void* d_out, int out_size, void* d_ws, size_t ws_size,
                              hipStream_t stream) {
    const float* x = (const float*)d_in[0];
    const float* Wq = (const float*)d_in[1];
    const float* Wk = (const float*)d_in[2];
    const float* Wv = (const float*)d_in[3];
    const float* Wo = (const float*)d_in[4];
    const float* Wiq = (const float*)d_in[5];
    const float* Wik = (const float*)d_in[6];
    const float* Wiw = (const float*)d_in[7];
    const float* biw = (const float*)d_in[8];
    const float* idx_bias = (const float*)d_in[9];
    const float* Wvg = (const float*)d_in[10];
    const float* bvg = (const float*)d_in[11];
    const float* Wog = (const float*)d_in[12];
    const float* bog = (const float*)d_in[13];
    float* out = (float*)d_out;
    char* base = (char*)d_ws;

    float* qb = (float*)(base + 0);
    float* kb = (float*)(base + (4ull << 20));
    float* vb = (float*)(base + (8ull << 20));
    float* vgb = (float*)(base + (12ull << 20));
    float* ogb = (float*)(base + (16ull << 20));
    float* qib = (float*)(base + (20ull << 20));
    float* kib = (float*)(base + (22ull << 20));
    float* wsb = (float*)(base + (22ull << 20) + (512u << 10));
    ushort* xb = (ushort*)(base + (23ull << 20));
    ushort* wtb = (ushort*)(base + (25ull << 20));
    ushort* kb16 = (ushort*)(base + (28ull << 20));
    ushort* vb16 = (ushort*)(base + (30ull << 20));
    unsigned* keysb = (unsigned*)(base + (32ull << 20));
    ushort* ab_bf = (ushort*)(base + (32ull << 20));
    int* idxb = (int*)(base + (12ull << 20));
    int* cntb = (int*)(base + (13ull << 20) + (512u << 10));

    dim3 blk(256);
    castx_kernel<<<TT * DD / 256, blk, 0, stream>>>(x, xb);
    wtrans_kernel<<<dim3(16, 16, 6), blk, 0, stream>>>(Wq, Wk, Wv, Wvg, Wog, Wo, wtb);
    proj32_kernel<<<dim3(5, 32), blk, 0, stream>>>(x, Wiq, Wik, qib, kib);
    iw_kernel<<<TT, blk, 0, stream>>>(x, Wiw, biw, wsb);
    mfma_gemm<<<dim3(20, 16), blk, 0, stream>>>(xb, wtb, qb, kb, vb, vgb, ogb,
                                                bvg, bog, nullptr, 0);
    vmul_kernel<<<(TT * DD) / 256, blk, 0, stream>>>(vb, vgb, vb16);
    rope_kernel<<<(TT * HEADS * 32) / 256, blk, 0, stream>>>(qb, kb, kb16);
    score_kernel<<<528, blk, 0, stream>>>(qib, kib, wsb, idx_bias, keysb);
    topk_kernel<<<TT, blk, 0, stream>>>(keysb, idxb, cntb);
    attn_kernel<<<TT, blk, 0, stream>>>(qb, kb16, vb16, ogb, idxb, cntb, ab_bf);
    mfma_gemm<<<dim3(4, 16), blk, 0, stream>>>(ab_bf, wtb + (size_t)5 * 512 * 512,
                                               nullptr, nullptr, nullptr, nullptr,
                                               nullptr, nullptr, nullptr, out, 1);
}